// Round 8
// baseline (570.332 us; speedup 1.0000x reference)
//
#include <hip/hip_runtime.h>
#include <hip/hip_bf16.h>
#include <cstdint>
#include <cstddef>

#define BB 8
#define HH 8
#define NN 1024
#define CC 256
#define OUTCH 4096   // 2*H*C

typedef __attribute__((ext_vector_type(8))) __bf16 bf16x8;
typedef __attribute__((ext_vector_type(4))) __bf16 bf16x4;
typedef __attribute__((ext_vector_type(4))) float f32x4;

// ---------------------------------------------------------------------------
// async global->LDS, 16B per lane, wave-uniform LDS base + lane*16
// ---------------------------------------------------------------------------
__device__ inline void async16(const void* g, void* l)
{
  __builtin_amdgcn_global_load_lds(
      reinterpret_cast<const __attribute__((address_space(1))) unsigned int*>(
          reinterpret_cast<uintptr_t>(g)),
      reinterpret_cast<__attribute__((address_space(3))) unsigned int*>(
          reinterpret_cast<uintptr_t>(l)),
      16, 0, 0);
}

__device__ inline float waveMax(float v) {
#pragma unroll
  for (int o = 32; o > 0; o >>= 1) v = fmaxf(v, __shfl_xor(v, o, 64));
  return v;
}
__device__ inline float waveSum(float v) {
#pragma unroll
  for (int o = 32; o > 0; o >>= 1) v += __shfl_xor(v, o, 64);
  return v;
}

// LDS bank-conflict swizzle (rule #21: linear gload_lds dest + inverse-swizzled
// global SOURCE + swizzled ds_read). S(row, c16) = c16 ^ ((row>>1)&3).
// Staging lane l covers (row = l>>2, c16_pos = l&3) -> fetch logical col:
__device__ inline int stage_scol(int lane) {
  return (((lane & 3) ^ ((lane >> 3) & 3))) * 8;   // elems
}
// Fragment read: row = base + (lane&15), logical c16 = lane>>4 ->
__device__ inline int frag_fb(int lane) {
  return (lane & 15) * 64 + (((lane >> 4) ^ (((lane & 15) >> 1) & 3)) << 4);  // bytes
}

// ---------------------------------------------------------------------------
// split f32 -> (hi, lo) bf16 planes
// ---------------------------------------------------------------------------
__global__ __launch_bounds__(256) void split_kernel(const float* __restrict__ in,
                                                    __bf16* __restrict__ hi,
                                                    __bf16* __restrict__ lo, int n4)
{
  const int i = blockIdx.x * 256 + threadIdx.x;
  if (i >= n4) return;
  const float4 v = ((const float4*)in)[i];
  bf16x4 h, l;
  h.x = (__bf16)v.x; l.x = (__bf16)(v.x - (float)h.x);
  h.y = (__bf16)v.y; l.y = (__bf16)(v.y - (float)h.y);
  h.z = (__bf16)v.z; l.z = (__bf16)(v.z - (float)h.z);
  h.w = (__bf16)v.w; l.w = (__bf16)(v.w - (float)h.w);
  ((bf16x4*)hi)[i] = h;
  ((bf16x4*)lo)[i] = l;
}

// ---------------------------------------------------------------------------
// Split-bf16 MFMA GEMM #1: qk = x @ W^T, written as hi/lo bf16 planes.
// ---------------------------------------------------------------------------
__global__ __launch_bounds__(256) void xw_mfma_kernel(
    const __bf16* __restrict__ Ah, const __bf16* __restrict__ Al,
    const __bf16* __restrict__ Bh, const __bf16* __restrict__ Bl,
    __bf16* __restrict__ Chi, __bf16* __restrict__ Clo)
{
  __shared__ __bf16 AsH[128 * 32], AsL[128 * 32], BsH[128 * 32], BsL[128 * 32];

  const int tid = threadIdx.x, lane = tid & 63, wid = tid >> 6;
  const int wr = wid >> 1, wc = wid & 1;
  const int bM = blockIdx.y * 128, bN = blockIdx.x * 128;

  const int srow = wid * 16 + (lane >> 2);
  const int scol = stage_scol(lane);
  const __bf16* gAh = Ah + (size_t)(bM + srow) * CC + scol;
  const __bf16* gAl = Al + (size_t)(bM + srow) * CC + scol;
  const __bf16* gBh = Bh + (size_t)(bN + srow) * CC + scol;
  const __bf16* gBl = Bl + (size_t)(bN + srow) * CC + scol;
  char* lAh = (char*)AsH + wid * 16 * 64;
  char* lAl = (char*)AsL + wid * 16 * 64;
  char* lBh = (char*)BsH + wid * 16 * 64;
  char* lBl = (char*)BsL + wid * 16 * 64;

  f32x4 acc[4][4];
  const f32x4 z = {0.f, 0.f, 0.f, 0.f};
#pragma unroll
  for (int m = 0; m < 4; ++m)
#pragma unroll
    for (int n = 0; n < 4; ++n) acc[m][n] = z;

  for (int k0 = 0; k0 < CC; k0 += 32) {
    async16(gAh + k0, lAh); async16(gAh + k0 + 64 * CC, lAh + 64 * 64);
    async16(gAl + k0, lAl); async16(gAl + k0 + 64 * CC, lAl + 64 * 64);
    async16(gBh + k0, lBh); async16(gBh + k0 + 64 * CC, lBh + 64 * 64);
    async16(gBl + k0, lBl); async16(gBl + k0 + 64 * CC, lBl + 64 * 64);
    __syncthreads();

    bf16x8 ah[4], al[4], bh_[4], bl_[4];
    const int fb = frag_fb(lane);
#pragma unroll
    for (int m = 0; m < 4; ++m) {
      ah[m] = *(const bf16x8*)((const char*)AsH + (wr * 64 + m * 16) * 64 + fb);
      al[m] = *(const bf16x8*)((const char*)AsL + (wr * 64 + m * 16) * 64 + fb);
    }
#pragma unroll
    for (int n = 0; n < 4; ++n) {
      bh_[n] = *(const bf16x8*)((const char*)BsH + (wc * 64 + n * 16) * 64 + fb);
      bl_[n] = *(const bf16x8*)((const char*)BsL + (wc * 64 + n * 16) * 64 + fb);
    }
#pragma unroll
    for (int m = 0; m < 4; ++m)
#pragma unroll
      for (int n = 0; n < 4; ++n) {
        acc[m][n] = __builtin_amdgcn_mfma_f32_16x16x32_bf16(al[m], bh_[n], acc[m][n], 0, 0, 0);
        acc[m][n] = __builtin_amdgcn_mfma_f32_16x16x32_bf16(ah[m], bl_[n], acc[m][n], 0, 0, 0);
        acc[m][n] = __builtin_amdgcn_mfma_f32_16x16x32_bf16(ah[m], bh_[n], acc[m][n], 0, 0, 0);
      }
    __syncthreads();
  }

  const int fr = lane & 15;
  const int fq = lane >> 4;
#pragma unroll
  for (int m = 0; m < 4; ++m) {
    const int row0 = bM + wr * 64 + m * 16 + fq * 4;
#pragma unroll
    for (int n = 0; n < 4; ++n) {
      const int col = bN + wc * 64 + n * 16 + fr;
#pragma unroll
      for (int r = 0; r < 4; ++r) {
        const float v = acc[m][n][r];
        const __bf16 h = (__bf16)v;
        const __bf16 l = (__bf16)(v - (float)h);
        Chi[(size_t)(row0 + r) * OUTCH + col] = h;
        Clo[(size_t)(row0 + r) * OUTCH + col] = l;
      }
    }
  }
}

// ---------------------------------------------------------------------------
// Split-bf16 MFMA GEMM #2: logits[b,h] = (1/16) * q_bh @ k_bh^T  -> f32
// 1D grid, bh-resident XCD swizzle: f = (bh%8) + 8*((bh/8)*64 + tile)
// ---------------------------------------------------------------------------
__global__ __launch_bounds__(256) void qkt_mfma_kernel(
    const __bf16* __restrict__ Qh, const __bf16* __restrict__ Ql,
    float* __restrict__ outall)
{
  const int f = blockIdx.x;
  const int xcd = f & 7;
  const int g = f >> 3;            // (bh/8)*64 + tile
  const int bh = xcd + 8 * (g >> 6);
  const int tile = g & 63;
  const int b = bh >> 3, h = bh & 7;
  const size_t qoff = (size_t)b * NN * OUTCH + (size_t)h * CC;
  const size_t koff = qoff + 2048;
  float* C = outall + ((size_t)bh << 20);

  __shared__ __bf16 AsH[128 * 32], AsL[128 * 32], BsH[128 * 32], BsL[128 * 32];

  const int tid = threadIdx.x, lane = tid & 63, wid = tid >> 6;
  const int wr = wid >> 1, wc = wid & 1;
  const int bM = (tile >> 3) * 128, bN = (tile & 7) * 128;

  const int srow = wid * 16 + (lane >> 2);
  const int scol = stage_scol(lane);
  const __bf16* gAh = Qh + qoff + (size_t)(bM + srow) * OUTCH + scol;
  const __bf16* gAl = Ql + qoff + (size_t)(bM + srow) * OUTCH + scol;
  const __bf16* gBh = Qh + koff + (size_t)(bN + srow) * OUTCH + scol;
  const __bf16* gBl = Ql + koff + (size_t)(bN + srow) * OUTCH + scol;
  char* lAh = (char*)AsH + wid * 16 * 64;
  char* lAl = (char*)AsL + wid * 16 * 64;
  char* lBh = (char*)BsH + wid * 16 * 64;
  char* lBl = (char*)BsL + wid * 16 * 64;

  f32x4 acc[4][4];
  const f32x4 z = {0.f, 0.f, 0.f, 0.f};
#pragma unroll
  for (int m = 0; m < 4; ++m)
#pragma unroll
    for (int n = 0; n < 4; ++n) acc[m][n] = z;

  for (int k0 = 0; k0 < CC; k0 += 32) {
    async16(gAh + k0, lAh); async16(gAh + k0 + (size_t)64 * OUTCH, lAh + 64 * 64);
    async16(gAl + k0, lAl); async16(gAl + k0 + (size_t)64 * OUTCH, lAl + 64 * 64);
    async16(gBh + k0, lBh); async16(gBh + k0 + (size_t)64 * OUTCH, lBh + 64 * 64);
    async16(gBl + k0, lBl); async16(gBl + k0 + (size_t)64 * OUTCH, lBl + 64 * 64);
    __syncthreads();

    bf16x8 ah[4], al[4], bh_[4], bl_[4];
    const int fb = frag_fb(lane);
#pragma unroll
    for (int m = 0; m < 4; ++m) {
      ah[m] = *(const bf16x8*)((const char*)AsH + (wr * 64 + m * 16) * 64 + fb);
      al[m] = *(const bf16x8*)((const char*)AsL + (wr * 64 + m * 16) * 64 + fb);
    }
#pragma unroll
    for (int n = 0; n < 4; ++n) {
      bh_[n] = *(const bf16x8*)((const char*)BsH + (wc * 64 + n * 16) * 64 + fb);
      bl_[n] = *(const bf16x8*)((const char*)BsL + (wc * 64 + n * 16) * 64 + fb);
    }
#pragma unroll
    for (int m = 0; m < 4; ++m)
#pragma unroll
      for (int n = 0; n < 4; ++n) {
        acc[m][n] = __builtin_amdgcn_mfma_f32_16x16x32_bf16(al[m], bh_[n], acc[m][n], 0, 0, 0);
        acc[m][n] = __builtin_amdgcn_mfma_f32_16x16x32_bf16(ah[m], bl_[n], acc[m][n], 0, 0, 0);
        acc[m][n] = __builtin_amdgcn_mfma_f32_16x16x32_bf16(ah[m], bh_[n], acc[m][n], 0, 0, 0);
      }
    __syncthreads();
  }

  const int fr = lane & 15;
  const int fq = lane >> 4;
#pragma unroll
  for (int m = 0; m < 4; ++m) {
    const int row0 = bM + wr * 64 + m * 16 + fq * 4;
#pragma unroll
    for (int n = 0; n < 4; ++n) {
      const int col = bN + wc * 64 + n * 16 + fr;
#pragma unroll
      for (int r = 0; r < 4; ++r)
        C[(size_t)(row0 + r) * NN + col] = acc[m][n][r] * 0.0625f;
    }
  }
}

// ---------------------------------------------------------------------------
// Fused softmax + head-sum. f32 logits (d_out) in, bf16 attn -> ws (contig),
// se from pre-rounding f32 values (top-k path bit-identical to f32 version).
// ---------------------------------------------------------------------------
__global__ __launch_bounds__(256) void softmax_se_kernel(const float* __restrict__ logits,
                                                         __bf16* __restrict__ attnb,
                                                         float* __restrict__ se)
{
  const int bn = blockIdx.x;
  const int b = bn >> 10;
  const int n = bn & 1023;
  const int t = threadIdx.x;
  const int lane = t & 63, wv = t >> 6;
  __shared__ float wred[4];
  float4 acc = make_float4(0.f, 0.f, 0.f, 0.f);

#pragma unroll 1
  for (int h = 0; h < HH; ++h) {
    const size_t rowbase = (((size_t)(b * HH + h) << 10) + n) << 10;
    const float* ar = logits + rowbase;
    __bf16* arb = attnb + rowbase;
    float4 x = *(const float4*)(ar + (t << 2));
    float mx = waveMax(fmaxf(fmaxf(x.x, x.y), fmaxf(x.z, x.w)));
    if (lane == 0) wred[wv] = mx;
    __syncthreads();
    const float M = fmaxf(fmaxf(wred[0], wred[1]), fmaxf(wred[2], wred[3]));
    __syncthreads();

    float e0 = expf(x.x - M), e1 = expf(x.y - M), e2 = expf(x.z - M), e3 = expf(x.w - M);
    float s = waveSum(e0 + e1 + e2 + e3);
    if (lane == 0) wred[wv] = s;
    __syncthreads();
    const float inv = 1.0f / (wred[0] + wred[1] + wred[2] + wred[3]);

    const float o0 = e0 * inv, o1 = e1 * inv, o2 = e2 * inv, o3 = e3 * inv;
    bf16x4 ob; ob.x = (__bf16)o0; ob.y = (__bf16)o1; ob.z = (__bf16)o2; ob.w = (__bf16)o3;
    *(bf16x4*)(arb + (t << 2)) = ob;
    acc.x += o0; acc.y += o1; acc.z += o2; acc.w += o3;
    __syncthreads();
  }
  *(float4*)(se + (size_t)bn * NN + (t << 2)) = acc;
}

// ---------------------------------------------------------------------------
// Top-5 per row of sum_edge; colmask[b, idx] = 1 for each winner.
// ---------------------------------------------------------------------------
__global__ __launch_bounds__(256) void topk_kernel(const float* __restrict__ se,
                                                   float* __restrict__ colmask)
{
  const int bn = blockIdx.x;
  const int b = bn >> 10;
  const int t = threadIdx.x;
  __shared__ float vals[NN];
  __shared__ unsigned long long red[256];
  const float* rowp = se + (size_t)bn * NN;
  for (int i = t; i < NN; i += 256) vals[i] = rowp[i];
  __syncthreads();

  for (int it = 0; it < 5; ++it) {
    unsigned long long best = 0ull;
    for (int i = t; i < NN; i += 256) {
      const float v = vals[i];
      if (v >= 0.f) {
        unsigned long long key =
            ((unsigned long long)__float_as_uint(v) << 32) | (unsigned)(NN - 1 - i);
        if (key > best) best = key;
      }
    }
    red[t] = best; __syncthreads();
    for (int s = 128; s > 0; s >>= 1) {
      if (t < s) red[t] = red[t] > red[t+s] ? red[t] : red[t+s];
      __syncthreads();
    }
    if (t == 0) {
      const int idx = NN - 1 - (int)(red[0] & 0xFFFFFFFFull);
      colmask[b * NN + idx] = 1.0f;
      vals[idx] = -1.0f;
    }
    __syncthreads();
  }
}

// ---------------------------------------------------------------------------
// Fused rs+cs stage 1. Grid (16, B*H); block handles 64 rows; wave per 16 rows.
// ---------------------------------------------------------------------------
__global__ __launch_bounds__(256) void cs_rs_kernel(const __bf16* __restrict__ attnb,
                                                    const float* __restrict__ colmask,
                                                    float* __restrict__ inv_rs,
                                                    float* __restrict__ part)
{
  const int bh = blockIdx.y;
  const int b = bh >> 3;
  const int chunk = blockIdx.x;        // 0..15
  const int t = threadIdx.x, lane = t & 63, wv = t >> 6;
  const __bf16* ab = attnb + ((size_t)bh << 20);
  const float* cm = colmask + b * NN;
  const int c0 = lane * 16;            // this lane's 16 columns

  float cmv[16];
#pragma unroll
  for (int q = 0; q < 4; ++q) {
    const float4 c4 = *(const float4*)(cm + c0 + q * 4);
    cmv[q*4+0] = c4.x; cmv[q*4+1] = c4.y; cmv[q*4+2] = c4.z; cmv[q*4+3] = c4.w;
  }

  float a[16];
#pragma unroll
  for (int j = 0; j < 16; ++j) a[j] = 0.f;

  const int nbase = chunk * 64 + wv * 16;
#pragma unroll 1
  for (int r = 0; r < 16; ++r) {
    const int n = nbase + r;
    const __bf16* rowp = ab + ((size_t)n << 10) + c0;
    const bf16x8 v0 = *(const bf16x8*)(rowp);
    const bf16x8 v1 = *(const bf16x8*)(rowp + 8);
    float e[16];
    float rsum = 0.f;
#pragma unroll
    for (int j = 0; j < 8; ++j) {
      const float val = ((cmv[j] != 0.f) || (c0 + j == n)) ? (float)v0[j] : 0.f;
      e[j] = val; rsum += val;
    }
#pragma unroll
    for (int j = 0; j < 8; ++j) {
      const float val = ((cmv[8+j] != 0.f) || (c0 + 8 + j == n)) ? (float)v1[j] : 0.f;
      e[8+j] = val; rsum += val;
    }
    rsum = waveSum(rsum);
    const float ir = 1.0f / (rsum + 1e-16f);
    if (lane == 0) inv_rs[bh * NN + n] = ir;
#pragma unroll
    for (int j = 0; j < 16; ++j) a[j] += e[j] * ir;
  }

  __shared__ float l[4][NN];
#pragma unroll
  for (int j = 0; j < 16; ++j) l[wv][c0 + j] = a[j];
  __syncthreads();
  const int m0 = t << 2;
  float4 o;
  o.x = l[0][m0+0] + l[1][m0+0] + l[2][m0+0] + l[3][m0+0];
  o.y = l[0][m0+1] + l[1][m0+1] + l[2][m0+1] + l[3][m0+1];
  o.z = l[0][m0+2] + l[1][m0+2] + l[2][m0+2] + l[3][m0+2];
  o.w = l[0][m0+3] + l[1][m0+3] + l[2][m0+3] + l[3][m0+3];
  *(float4*)(part + (((size_t)chunk * (BB*HH) + bh) << 10) + m0) = o;
}

// ---------------------------------------------------------------------------
// cs stage 2: isc = rsqrt(sum_c part + eps)
// ---------------------------------------------------------------------------
__global__ __launch_bounds__(256) void cs_fin_kernel(const float* __restrict__ part,
                                                     float* __restrict__ isc)
{
  const int bh = blockIdx.x;
  const int m0 = threadIdx.x << 2;
  float a0 = 0.f, a1 = 0.f, a2 = 0.f, a3 = 0.f;
#pragma unroll
  for (int c = 0; c < 16; ++c) {
    const float4 p = *(const float4*)(part + (((size_t)c * (BB*HH) + bh) << 10) + m0);
    a0 += p.x; a1 += p.y; a2 += p.z; a3 += p.w;
  }
  float4 o;
  o.x = 1.0f / sqrtf(a0 + 1e-16f);
  o.y = 1.0f / sqrtf(a1 + 1e-16f);
  o.z = 1.0f / sqrtf(a2 + 1e-16f);
  o.w = 1.0f / sqrtf(a3 + 1e-16f);
  *(float4*)(isc + ((size_t)bh << 10) + m0) = o;
}

// ---------------------------------------------------------------------------
// Gb[b,h,n,m] = bf16( e * inv_rs[n] * isc[m] ), e from contiguous bf16 attn.
// ---------------------------------------------------------------------------
__global__ __launch_bounds__(256) void g_kernel(const __bf16* __restrict__ attnb,
                                                const float* __restrict__ colmask,
                                                const float* __restrict__ inv_rs,
                                                const float* __restrict__ isc,
                                                __bf16* __restrict__ Gb)
{
  const size_t idx = ((size_t)blockIdx.x * 256 + threadIdx.x) << 2;
  const size_t row = idx >> 10;
  const int m = (int)(idx & 1023);
  const int n = (int)(row & 1023);
  const int bh = (int)(row >> 10);
  const int b = bh >> 3;
  const bf16x4 vb = *(const bf16x4*)(attnb + idx);
  const float4 c = *(const float4*)(colmask + b * NN + m);
  const float4 s = *(const float4*)(isc + ((size_t)bh << 10) + m);
  const float ir = inv_rs[row];
  bf16x4 o;
  o.x = (__bf16)((((c.x != 0.f) || (m + 0 == n)) ? (float)vb.x : 0.f) * ir * s.x);
  o.y = (__bf16)((((c.y != 0.f) || (m + 1 == n)) ? (float)vb.y : 0.f) * ir * s.y);
  o.z = (__bf16)((((c.z != 0.f) || (m + 2 == n)) ? (float)vb.z : 0.f) * ir * s.z);
  o.w = (__bf16)((((c.w != 0.f) || (m + 3 == n)) ? (float)vb.w : 0.f) * ir * s.w);
  *(bf16x4*)(Gb + idx) = o;
}

// ---------------------------------------------------------------------------
// out[b,h] = Gb @ Gb^T (symmetric, upper-triangle tiles, mirrored writes).
// 1D grid, bh-resident XCD swizzle: f = (bh%8) + 8*((bh/8)*36 + tri)
// ---------------------------------------------------------------------------
__global__ __launch_bounds__(256) void ggt_mfma_kernel(const __bf16* __restrict__ Gball,
                                                       float* __restrict__ outall)
{
  const int f = blockIdx.x;
  const int xcd = f & 7;
  const int g = f >> 3;               // (bh/8)*36 + tri
  const int bh = xcd + 8 * (g / 36);
  int tt = g % 36;

  const __bf16* A = Gball + ((size_t)bh << 20);
  float* C = outall + ((size_t)bh << 20);

  int ti = 0;
#pragma unroll
  for (int r = 0; r < 8; ++r) {
    const int len = 8 - r;
    if (tt < len) { ti = r; break; }
    tt -= len;
  }
  const int tj = ti + tt;

  __shared__ __bf16 As[128 * 32];
  __shared__ __bf16 Bs[128 * 32];

  const int tid  = threadIdx.x;
  const int lane = tid & 63;
  const int wid  = tid >> 6;
  const int wr   = wid >> 1;
  const int wc   = wid & 1;
  const int bM   = ti * 128;
  const int bN   = tj * 128;

  const int srow = wid * 16 + (lane >> 2);
  const int scol = stage_scol(lane);
  const __bf16* gA = A + (size_t)(bM + srow) * NN + scol;
  const __bf16* gB = A + (size_t)(bN + srow) * NN + scol;
  char* lA = (char*)As + wid * 16 * 64;
  char* lB = (char*)Bs + wid * 16 * 64;

  f32x4 acc[4][4];
  const f32x4 z = {0.f, 0.f, 0.f, 0.f};
#pragma unroll
  for (int m = 0; m < 4; ++m)
#pragma unroll
    for (int n = 0; n < 4; ++n) acc[m][n] = z;

  for (int k0 = 0; k0 < NN; k0 += 32) {
    async16(gA + k0,           lA);
    async16(gA + k0 + 64 * NN, lA + 64 * 64);
    async16(gB + k0,           lB);
    async16(gB + k0 + 64 * NN, lB + 64 * 64);
    __syncthreads();

    bf16x8 a[4], b[4];
    const int fb = frag_fb(lane);
#pragma unroll
    for (int m = 0; m < 4; ++m)
      a[m] = *(const bf16x8*)((const char*)As + (wr * 64 + m * 16) * 64 + fb);
#pragma unroll
    for (int n = 0; n < 4; ++n)
      b[n] = *(const bf16x8*)((const char*)Bs + (wc * 64 + n * 16) * 64 + fb);
#pragma unroll
    for (int m = 0; m < 4; ++m)
#pragma unroll
      for (int n = 0; n < 4; ++n)
        acc[m][n] = __builtin_amdgcn_mfma_f32_16x16x32_bf16(a[m], b[n], acc[m][n], 0, 0, 0);
    __syncthreads();
  }

  const int fr = lane & 15;
  const int fq = lane >> 4;
#pragma unroll
  for (int m = 0; m < 4; ++m) {
    const int row0 = bM + wr * 64 + m * 16 + fq * 4;
#pragma unroll
    for (int n = 0; n < 4; ++n) {
      const int col = bN + wc * 64 + n * 16 + fr;
#pragma unroll
      for (int r = 0; r < 4; ++r)
        C[(size_t)(row0 + r) * NN + col] = acc[m][n][r];
    }
  }
  if (ti != tj) {
#pragma unroll
    for (int m = 0; m < 4; ++m) {
      const int colT = bM + wr * 64 + m * 16 + fq * 4;
#pragma unroll
      for (int n = 0; n < 4; ++n) {
        const int rowT = bN + wc * 64 + n * 16 + fr;
        *(f32x4*)(C + (size_t)rowT * NN + colT) = acc[m][n];
      }
    }
  }
}

// ---------------------------------------------------------------------------
extern "C" void kernel_launch(void* const* d_in, const int* in_sizes, int n_in,
                              void* d_out, int out_size, void* d_ws, size_t ws_size,
                              hipStream_t stream)
{
  const float* x = (const float*)d_in[0];   // [B,N,C]
  const float* W = (const float*)d_in[1];   // [2*H*C, C]
  float* logits = (float*)d_out;            // f32 logits, later final out
  char* ws = (char*)d_ws;

  __bf16* qk_hi = (__bf16*)(ws + ((size_t)0   << 20));   // 64 MiB
  __bf16* qk_lo = (__bf16*)(ws + ((size_t)64  << 20));   // 64 MiB
  __bf16* attnb = (__bf16*)(ws + ((size_t)0   << 20));   // 128 MiB (reuses qk)
  __bf16* x_hi  = (__bf16*)(ws + ((size_t)128 << 20));
  __bf16* x_lo  = (__bf16*)(ws + ((size_t)132 << 20));
  __bf16* W_hi  = (__bf16*)(ws + ((size_t)136 << 20));
  __bf16* W_lo  = (__bf16*)(ws + ((size_t)138 << 20));
  float*  se    = (float*)(ws + ((size_t)144 << 20));    // 32 MiB
  float*  cmask = (float*)(ws + ((size_t)176 << 20));    // 32 KiB
  float*  irs   = (float*)(ws + ((size_t)177 << 20));    // 256 KiB
  float*  isc   = (float*)(ws + ((size_t)178 << 20));    // 256 KiB
  float*  csp   = (float*)(ws + ((size_t)180 << 20));    // 4 MiB partials
  __bf16* Gb    = (__bf16*)(ws + ((size_t)192 << 20));   // 128 MiB

  // 0. split x and W into bf16 hi/lo
  hipLaunchKernelGGL(split_kernel, dim3((BB*NN*CC/4 + 255)/256), dim3(256), 0, stream,
                     x, x_hi, x_lo, BB*NN*CC/4);
  hipLaunchKernelGGL(split_kernel, dim3((OUTCH*CC/4 + 255)/256), dim3(256), 0, stream,
                     W, W_hi, W_lo, OUTCH*CC/4);

  // 1. qk = x @ W^T (split-bf16 MFMA)
  hipLaunchKernelGGL(xw_mfma_kernel, dim3(OUTCH/128, (BB*NN)/128, 1), dim3(256), 0, stream,
                     x_hi, x_lo, W_hi, W_lo, qk_hi, qk_lo);

  // 2. logits = scale * q @ k^T -> d_out (f32), bh-resident swizzle
  hipLaunchKernelGGL(qkt_mfma_kernel, dim3(64 * 64), dim3(256), 0, stream,
                     qk_hi, qk_lo, logits);

  // 3+4. softmax (f32 logits -> bf16 attn in ws) + head-sum
  hipLaunchKernelGGL(softmax_se_kernel, dim3(BB*NN), dim3(256), 0, stream,
                     logits, attnb, se);

  // 5. top-5 union -> column mask
  hipMemsetAsync(cmask, 0, (size_t)BB * NN * 4, stream);
  hipLaunchKernelGGL(topk_kernel, dim3(BB*NN), dim3(256), 0, stream, se, cmask);

  // 6+7. fused row sums + column partials, then finalize isc
  hipLaunchKernelGGL(cs_rs_kernel, dim3(16, BB*HH), dim3(256), 0, stream,
                     attnb, cmask, irs, csp);
  hipLaunchKernelGGL(cs_fin_kernel, dim3(BB*HH), dim3(256), 0, stream, csp, isc);

  // 8. Gb = bf16( e * inv_rs * isc )
  hipLaunchKernelGGL(g_kernel, dim3((BB*HH*NN*(long long)NN) / 4 / 256), dim3(256), 0, stream,
                     attnb, cmask, irs, isc, Gb);

  // 9. out = Gb @ Gb^T (symmetric MFMA, bh-resident swizzle) -> d_out f32
  hipLaunchKernelGGL(ggt_mfma_kernel, dim3(36 * 64), dim3(256), 0, stream,
                     Gb, logits);

  (void)in_sizes; (void)n_in; (void)out_size; (void)ws_size;
}

// Round 9
// 552.955 us; speedup vs baseline: 1.0314x; 1.0314x over previous
//
#include <hip/hip_runtime.h>
#include <hip/hip_bf16.h>
#include <cstdint>
#include <cstddef>

#define BB 8
#define HH 8
#define NN 1024
#define CC 256
#define OUTCH 4096   // 2*H*C

typedef __attribute__((ext_vector_type(8))) __bf16 bf16x8;
typedef __attribute__((ext_vector_type(4))) __bf16 bf16x4;
typedef __attribute__((ext_vector_type(4))) float f32x4;

// ---------------------------------------------------------------------------
// async global->LDS, 16B per lane, wave-uniform LDS base + lane*16
// ---------------------------------------------------------------------------
__device__ inline void async16(const void* g, void* l)
{
  __builtin_amdgcn_global_load_lds(
      reinterpret_cast<const __attribute__((address_space(1))) unsigned int*>(
          reinterpret_cast<uintptr_t>(g)),
      reinterpret_cast<__attribute__((address_space(3))) unsigned int*>(
          reinterpret_cast<uintptr_t>(l)),
      16, 0, 0);
}

__device__ inline float waveMax(float v) {
#pragma unroll
  for (int o = 32; o > 0; o >>= 1) v = fmaxf(v, __shfl_xor(v, o, 64));
  return v;
}
__device__ inline float waveSum(float v) {
#pragma unroll
  for (int o = 32; o > 0; o >>= 1) v += __shfl_xor(v, o, 64);
  return v;
}

// ---------------------------------------------------------------------------
// split x and W into bf16 hi/lo planes (single launch)
// ---------------------------------------------------------------------------
__global__ __launch_bounds__(256) void split2_kernel(
    const float* __restrict__ x, const float* __restrict__ W,
    __bf16* __restrict__ xh, __bf16* __restrict__ xl,
    __bf16* __restrict__ Wh, __bf16* __restrict__ Wl)
{
  const int NX = BB * NN * CC / 4;
  int i = blockIdx.x * 256 + threadIdx.x;
  const float* in; __bf16* ph; __bf16* pl; int j;
  if (i < NX) { in = x; ph = xh; pl = xl; j = i; }
  else        { in = W; ph = Wh; pl = Wl; j = i - NX; }
  const float4 v = ((const float4*)in)[j];
  bf16x4 h, l;
  h.x = (__bf16)v.x; l.x = (__bf16)(v.x - (float)h.x);
  h.y = (__bf16)v.y; l.y = (__bf16)(v.y - (float)h.y);
  h.z = (__bf16)v.z; l.z = (__bf16)(v.z - (float)h.z);
  h.w = (__bf16)v.w; l.w = (__bf16)(v.w - (float)h.w);
  ((bf16x4*)ph)[j] = h;
  ((bf16x4*)pl)[j] = l;
}

// ---------------------------------------------------------------------------
// Split-bf16 MFMA GEMM #1: qk = x @ W^T, written as hi/lo bf16 planes.
// ---------------------------------------------------------------------------
__global__ __launch_bounds__(256) void xw_mfma_kernel(
    const __bf16* __restrict__ Ah, const __bf16* __restrict__ Al,
    const __bf16* __restrict__ Bh, const __bf16* __restrict__ Bl,
    __bf16* __restrict__ Chi, __bf16* __restrict__ Clo)
{
  __shared__ __bf16 AsH[128 * 32], AsL[128 * 32], BsH[128 * 32], BsL[128 * 32];

  const int tid = threadIdx.x, lane = tid & 63, wid = tid >> 6;
  const int wr = wid >> 1, wc = wid & 1;
  const int bM = blockIdx.y * 128, bN = blockIdx.x * 128;

  const int srow = wid * 16 + (lane >> 2);
  const int scol = (lane & 3) * 8;
  const __bf16* gAh = Ah + (size_t)(bM + srow) * CC + scol;
  const __bf16* gAl = Al + (size_t)(bM + srow) * CC + scol;
  const __bf16* gBh = Bh + (size_t)(bN + srow) * CC + scol;
  const __bf16* gBl = Bl + (size_t)(bN + srow) * CC + scol;
  char* lAh = (char*)AsH + wid * 16 * 64;
  char* lAl = (char*)AsL + wid * 16 * 64;
  char* lBh = (char*)BsH + wid * 16 * 64;
  char* lBl = (char*)BsL + wid * 16 * 64;

  f32x4 acc[4][4];
  const f32x4 z = {0.f, 0.f, 0.f, 0.f};
#pragma unroll
  for (int m = 0; m < 4; ++m)
#pragma unroll
    for (int n = 0; n < 4; ++n) acc[m][n] = z;

  for (int k0 = 0; k0 < CC; k0 += 32) {
    async16(gAh + k0, lAh); async16(gAh + k0 + 64 * CC, lAh + 64 * 64);
    async16(gAl + k0, lAl); async16(gAl + k0 + 64 * CC, lAl + 64 * 64);
    async16(gBh + k0, lBh); async16(gBh + k0 + 64 * CC, lBh + 64 * 64);
    async16(gBl + k0, lBl); async16(gBl + k0 + 64 * CC, lBl + 64 * 64);
    __syncthreads();

    bf16x8 ah[4], al[4], bh_[4], bl_[4];
    const int fb = (lane & 15) * 64 + (lane >> 4) * 16;
#pragma unroll
    for (int m = 0; m < 4; ++m) {
      ah[m] = *(const bf16x8*)((const char*)AsH + (wr * 64 + m * 16) * 64 + fb);
      al[m] = *(const bf16x8*)((const char*)AsL + (wr * 64 + m * 16) * 64 + fb);
    }
#pragma unroll
    for (int n = 0; n < 4; ++n) {
      bh_[n] = *(const bf16x8*)((const char*)BsH + (wc * 64 + n * 16) * 64 + fb);
      bl_[n] = *(const bf16x8*)((const char*)BsL + (wc * 64 + n * 16) * 64 + fb);
    }
#pragma unroll
    for (int m = 0; m < 4; ++m)
#pragma unroll
      for (int n = 0; n < 4; ++n) {
        acc[m][n] = __builtin_amdgcn_mfma_f32_16x16x32_bf16(al[m], bh_[n], acc[m][n], 0, 0, 0);
        acc[m][n] = __builtin_amdgcn_mfma_f32_16x16x32_bf16(ah[m], bl_[n], acc[m][n], 0, 0, 0);
        acc[m][n] = __builtin_amdgcn_mfma_f32_16x16x32_bf16(ah[m], bh_[n], acc[m][n], 0, 0, 0);
      }
    __syncthreads();
  }

  const int fr = lane & 15;
  const int fq = lane >> 4;
#pragma unroll
  for (int m = 0; m < 4; ++m) {
    const int row0 = bM + wr * 64 + m * 16 + fq * 4;
#pragma unroll
    for (int n = 0; n < 4; ++n) {
      const int col = bN + wc * 64 + n * 16 + fr;
#pragma unroll
      for (int r = 0; r < 4; ++r) {
        const float v = acc[m][n][r];
        const __bf16 h = (__bf16)v;
        const __bf16 l = (__bf16)(v - (float)h);
        Chi[(size_t)(row0 + r) * OUTCH + col] = h;
        Clo[(size_t)(row0 + r) * OUTCH + col] = l;
      }
    }
  }
}

// ---------------------------------------------------------------------------
// Split-bf16 MFMA GEMM #2: logits[b,h] = (1/16) * q_bh @ k_bh^T  -> f32
// 1D grid, bh-resident XCD swizzle: f = (bh%8) + 8*((bh/8)*64 + tile)
// ---------------------------------------------------------------------------
__global__ __launch_bounds__(256) void qkt_mfma_kernel(
    const __bf16* __restrict__ Qh, const __bf16* __restrict__ Ql,
    float* __restrict__ outall)
{
  const int f = blockIdx.x;
  const int xcd = f & 7;
  const int g = f >> 3;            // (bh/8)*64 + tile
  const int bh = xcd + 8 * (g >> 6);
  const int tile = g & 63;
  const int b = bh >> 3, h = bh & 7;
  const size_t qoff = (size_t)b * NN * OUTCH + (size_t)h * CC;
  const size_t koff = qoff + 2048;
  float* C = outall + ((size_t)bh << 20);

  __shared__ __bf16 AsH[128 * 32], AsL[128 * 32], BsH[128 * 32], BsL[128 * 32];

  const int tid = threadIdx.x, lane = tid & 63, wid = tid >> 6;
  const int wr = wid >> 1, wc = wid & 1;
  const int bM = (tile >> 3) * 128, bN = (tile & 7) * 128;

  const int srow = wid * 16 + (lane >> 2);
  const int scol = (lane & 3) * 8;
  const __bf16* gAh = Qh + qoff + (size_t)(bM + srow) * OUTCH + scol;
  const __bf16* gAl = Ql + qoff + (size_t)(bM + srow) * OUTCH + scol;
  const __bf16* gBh = Qh + koff + (size_t)(bN + srow) * OUTCH + scol;
  const __bf16* gBl = Ql + koff + (size_t)(bN + srow) * OUTCH + scol;
  char* lAh = (char*)AsH + wid * 16 * 64;
  char* lAl = (char*)AsL + wid * 16 * 64;
  char* lBh = (char*)BsH + wid * 16 * 64;
  char* lBl = (char*)BsL + wid * 16 * 64;

  f32x4 acc[4][4];
  const f32x4 z = {0.f, 0.f, 0.f, 0.f};
#pragma unroll
  for (int m = 0; m < 4; ++m)
#pragma unroll
    for (int n = 0; n < 4; ++n) acc[m][n] = z;

  for (int k0 = 0; k0 < CC; k0 += 32) {
    async16(gAh + k0, lAh); async16(gAh + k0 + (size_t)64 * OUTCH, lAh + 64 * 64);
    async16(gAl + k0, lAl); async16(gAl + k0 + (size_t)64 * OUTCH, lAl + 64 * 64);
    async16(gBh + k0, lBh); async16(gBh + k0 + (size_t)64 * OUTCH, lBh + 64 * 64);
    async16(gBl + k0, lBl); async16(gBl + k0 + (size_t)64 * OUTCH, lBl + 64 * 64);
    __syncthreads();

    bf16x8 ah[4], al[4], bh_[4], bl_[4];
    const int fb = (lane & 15) * 64 + (lane >> 4) * 16;
#pragma unroll
    for (int m = 0; m < 4; ++m) {
      ah[m] = *(const bf16x8*)((const char*)AsH + (wr * 64 + m * 16) * 64 + fb);
      al[m] = *(const bf16x8*)((const char*)AsL + (wr * 64 + m * 16) * 64 + fb);
    }
#pragma unroll
    for (int n = 0; n < 4; ++n) {
      bh_[n] = *(const bf16x8*)((const char*)BsH + (wc * 64 + n * 16) * 64 + fb);
      bl_[n] = *(const bf16x8*)((const char*)BsL + (wc * 64 + n * 16) * 64 + fb);
    }
#pragma unroll
    for (int m = 0; m < 4; ++m)
#pragma unroll
      for (int n = 0; n < 4; ++n) {
        acc[m][n] = __builtin_amdgcn_mfma_f32_16x16x32_bf16(al[m], bh_[n], acc[m][n], 0, 0, 0);
        acc[m][n] = __builtin_amdgcn_mfma_f32_16x16x32_bf16(ah[m], bl_[n], acc[m][n], 0, 0, 0);
        acc[m][n] = __builtin_amdgcn_mfma_f32_16x16x32_bf16(ah[m], bh_[n], acc[m][n], 0, 0, 0);
      }
    __syncthreads();
  }

  const int fr = lane & 15;
  const int fq = lane >> 4;
#pragma unroll
  for (int m = 0; m < 4; ++m) {
    const int row0 = bM + wr * 64 + m * 16 + fq * 4;
#pragma unroll
    for (int n = 0; n < 4; ++n) {
      const int col = bN + wc * 64 + n * 16 + fr;
#pragma unroll
      for (int r = 0; r < 4; ++r)
        C[(size_t)(row0 + r) * NN + col] = acc[m][n][r] * 0.0625f;
    }
  }
}

// ---------------------------------------------------------------------------
// Fused softmax + head-sum. f32 logits (d_out) in, bf16 attn -> ws (contig),
// se from pre-rounding f32 values (top-k path bit-identical to f32 version).
// ---------------------------------------------------------------------------
__global__ __launch_bounds__(256) void softmax_se_kernel(const float* __restrict__ logits,
                                                         __bf16* __restrict__ attnb,
                                                         float* __restrict__ se)
{
  const int bn = blockIdx.x;
  const int b = bn >> 10;
  const int n = bn & 1023;
  const int t = threadIdx.x;
  const int lane = t & 63, wv = t >> 6;
  __shared__ float wred[4];
  float4 acc = make_float4(0.f, 0.f, 0.f, 0.f);

#pragma unroll 1
  for (int h = 0; h < HH; ++h) {
    const size_t rowbase = (((size_t)(b * HH + h) << 10) + n) << 10;
    const float* ar = logits + rowbase;
    __bf16* arb = attnb + rowbase;
    float4 x = *(const float4*)(ar + (t << 2));
    float mx = waveMax(fmaxf(fmaxf(x.x, x.y), fmaxf(x.z, x.w)));
    if (lane == 0) wred[wv] = mx;
    __syncthreads();
    const float M = fmaxf(fmaxf(wred[0], wred[1]), fmaxf(wred[2], wred[3]));
    __syncthreads();

    float e0 = expf(x.x - M), e1 = expf(x.y - M), e2 = expf(x.z - M), e3 = expf(x.w - M);
    float s = waveSum(e0 + e1 + e2 + e3);
    if (lane == 0) wred[wv] = s;
    __syncthreads();
    const float inv = 1.0f / (wred[0] + wred[1] + wred[2] + wred[3]);

    const float o0 = e0 * inv, o1 = e1 * inv, o2 = e2 * inv, o3 = e3 * inv;
    bf16x4 ob; ob.x = (__bf16)o0; ob.y = (__bf16)o1; ob.z = (__bf16)o2; ob.w = (__bf16)o3;
    *(bf16x4*)(arb + (t << 2)) = ob;
    acc.x += o0; acc.y += o1; acc.z += o2; acc.w += o3;
    __syncthreads();
  }
  *(float4*)(se + (size_t)bn * NN + (t << 2)) = acc;
}

// ---------------------------------------------------------------------------
// Top-5 per row of sum_edge; colmask[b, idx] = 1 for each winner.
// ---------------------------------------------------------------------------
__global__ __launch_bounds__(256) void topk_kernel(const float* __restrict__ se,
                                                   float* __restrict__ colmask)
{
  const int bn = blockIdx.x;
  const int b = bn >> 10;
  const int t = threadIdx.x;
  __shared__ float vals[NN];
  __shared__ unsigned long long red[256];
  const float* rowp = se + (size_t)bn * NN;
  for (int i = t; i < NN; i += 256) vals[i] = rowp[i];
  __syncthreads();

  for (int it = 0; it < 5; ++it) {
    unsigned long long best = 0ull;
    for (int i = t; i < NN; i += 256) {
      const float v = vals[i];
      if (v >= 0.f) {
        unsigned long long key =
            ((unsigned long long)__float_as_uint(v) << 32) | (unsigned)(NN - 1 - i);
        if (key > best) best = key;
      }
    }
    red[t] = best; __syncthreads();
    for (int s = 128; s > 0; s >>= 1) {
      if (t < s) red[t] = red[t] > red[t+s] ? red[t] : red[t+s];
      __syncthreads();
    }
    if (t == 0) {
      const int idx = NN - 1 - (int)(red[0] & 0xFFFFFFFFull);
      colmask[b * NN + idx] = 1.0f;
      vals[idx] = -1.0f;
    }
    __syncthreads();
  }
}

// ---------------------------------------------------------------------------
// Fused rs+cs stage 1. Grid (16, B*H); block handles 64 rows; wave per 16 rows.
// ---------------------------------------------------------------------------
__global__ __launch_bounds__(256) void cs_rs_kernel(const __bf16* __restrict__ attnb,
                                                    const float* __restrict__ colmask,
                                                    float* __restrict__ inv_rs,
                                                    float* __restrict__ part)
{
  const int bh = blockIdx.y;
  const int b = bh >> 3;
  const int chunk = blockIdx.x;        // 0..15
  const int t = threadIdx.x, lane = t & 63, wv = t >> 6;
  const __bf16* ab = attnb + ((size_t)bh << 20);
  const float* cm = colmask + b * NN;
  const int c0 = lane * 16;            // this lane's 16 columns

  float cmv[16];
#pragma unroll
  for (int q = 0; q < 4; ++q) {
    const float4 c4 = *(const float4*)(cm + c0 + q * 4);
    cmv[q*4+0] = c4.x; cmv[q*4+1] = c4.y; cmv[q*4+2] = c4.z; cmv[q*4+3] = c4.w;
  }

  float a[16];
#pragma unroll
  for (int j = 0; j < 16; ++j) a[j] = 0.f;

  const int nbase = chunk * 64 + wv * 16;
#pragma unroll 1
  for (int r = 0; r < 16; ++r) {
    const int n = nbase + r;
    const __bf16* rowp = ab + ((size_t)n << 10) + c0;
    const bf16x8 v0 = *(const bf16x8*)(rowp);
    const bf16x8 v1 = *(const bf16x8*)(rowp + 8);
    float e[16];
    float rsum = 0.f;
#pragma unroll
    for (int j = 0; j < 8; ++j) {
      const float val = ((cmv[j] != 0.f) || (c0 + j == n)) ? (float)v0[j] : 0.f;
      e[j] = val; rsum += val;
    }
#pragma unroll
    for (int j = 0; j < 8; ++j) {
      const float val = ((cmv[8+j] != 0.f) || (c0 + 8 + j == n)) ? (float)v1[j] : 0.f;
      e[8+j] = val; rsum += val;
    }
    rsum = waveSum(rsum);
    const float ir = 1.0f / (rsum + 1e-16f);
    if (lane == 0) inv_rs[bh * NN + n] = ir;
#pragma unroll
    for (int j = 0; j < 16; ++j) a[j] += e[j] * ir;
  }

  __shared__ float l[4][NN];
#pragma unroll
  for (int j = 0; j < 16; ++j) l[wv][c0 + j] = a[j];
  __syncthreads();
  const int m0 = t << 2;
  float4 o;
  o.x = l[0][m0+0] + l[1][m0+0] + l[2][m0+0] + l[3][m0+0];
  o.y = l[0][m0+1] + l[1][m0+1] + l[2][m0+1] + l[3][m0+1];
  o.z = l[0][m0+2] + l[1][m0+2] + l[2][m0+2] + l[3][m0+2];
  o.w = l[0][m0+3] + l[1][m0+3] + l[2][m0+3] + l[3][m0+3];
  *(float4*)(part + (((size_t)chunk * (BB*HH) + bh) << 10) + m0) = o;
}

// ---------------------------------------------------------------------------
// cs stage 2: isc = rsqrt(sum_c part + eps)
// ---------------------------------------------------------------------------
__global__ __launch_bounds__(256) void cs_fin_kernel(const float* __restrict__ part,
                                                     float* __restrict__ isc)
{
  const int bh = blockIdx.x;
  const int m0 = threadIdx.x << 2;
  float a0 = 0.f, a1 = 0.f, a2 = 0.f, a3 = 0.f;
#pragma unroll
  for (int c = 0; c < 16; ++c) {
    const float4 p = *(const float4*)(part + (((size_t)c * (BB*HH) + bh) << 10) + m0);
    a0 += p.x; a1 += p.y; a2 += p.z; a3 += p.w;
  }
  float4 o;
  o.x = 1.0f / sqrtf(a0 + 1e-16f);
  o.y = 1.0f / sqrtf(a1 + 1e-16f);
  o.z = 1.0f / sqrtf(a2 + 1e-16f);
  o.w = 1.0f / sqrtf(a3 + 1e-16f);
  *(float4*)(isc + ((size_t)bh << 10) + m0) = o;
}

// ---------------------------------------------------------------------------
// Gb[b,h,n,m] = bf16( e * inv_rs[n] * isc[m] ), e from contiguous bf16 attn.
// ---------------------------------------------------------------------------
__global__ __launch_bounds__(256) void g_kernel(const __bf16* __restrict__ attnb,
                                                const float* __restrict__ colmask,
                                                const float* __restrict__ inv_rs,
                                                const float* __restrict__ isc,
                                                __bf16* __restrict__ Gb)
{
  const size_t idx = ((size_t)blockIdx.x * 256 + threadIdx.x) << 2;
  const size_t row = idx >> 10;
  const int m = (int)(idx & 1023);
  const int n = (int)(row & 1023);
  const int bh = (int)(row >> 10);
  const int b = bh >> 3;
  const bf16x4 vb = *(const bf16x4*)(attnb + idx);
  const float4 c = *(const float4*)(colmask + b * NN + m);
  const float4 s = *(const float4*)(isc + ((size_t)bh << 10) + m);
  const float ir = inv_rs[row];
  bf16x4 o;
  o.x = (__bf16)((((c.x != 0.f) || (m + 0 == n)) ? (float)vb.x : 0.f) * ir * s.x);
  o.y = (__bf16)((((c.y != 0.f) || (m + 1 == n)) ? (float)vb.y : 0.f) * ir * s.y);
  o.z = (__bf16)((((c.z != 0.f) || (m + 2 == n)) ? (float)vb.z : 0.f) * ir * s.z);
  o.w = (__bf16)((((c.w != 0.f) || (m + 3 == n)) ? (float)vb.w : 0.f) * ir * s.w);
  *(bf16x4*)(Gb + idx) = o;
}

// ---------------------------------------------------------------------------
// out[b,h] = Gb @ Gb^T (symmetric, upper-triangle tiles, mirrored writes).
// Double-buffered LDS + raw s_barrier + counted vmcnt(4): next tile's
// global_load_lds stay in flight across the MFMA phase (T4 mechanism).
// 1D grid, bh-resident XCD swizzle: f = (bh%8) + 8*((bh/8)*36 + tri)
// ---------------------------------------------------------------------------
__global__ __launch_bounds__(256) void ggt_mfma_kernel(const __bf16* __restrict__ Gball,
                                                       float* __restrict__ outall)
{
  const int f = blockIdx.x;
  const int xcd = f & 7;
  const int g = f >> 3;               // (bh/8)*36 + tri
  const int bh = xcd + 8 * (g / 36);
  int tt = g % 36;

  const __bf16* A = Gball + ((size_t)bh << 20);
  float* C = outall + ((size_t)bh << 20);

  int ti = 0;
#pragma unroll
  for (int r = 0; r < 8; ++r) {
    const int len = 8 - r;
    if (tt < len) { ti = r; break; }
    tt -= len;
  }
  const int tj = ti + tt;

  __shared__ __bf16 As[2][128 * 32];
  __shared__ __bf16 Bs[2][128 * 32];

  const int tid  = threadIdx.x;
  const int lane = tid & 63;
  const int wid  = tid >> 6;
  const int wr   = wid >> 1;
  const int wc   = wid & 1;
  const int bM   = ti * 128;
  const int bN   = tj * 128;

  const int srow = wid * 16 + (lane >> 2);
  const int scol = (lane & 3) * 8;
  const __bf16* gA = A + (size_t)(bM + srow) * NN + scol;
  const __bf16* gB = A + (size_t)(bN + srow) * NN + scol;
  const int lofs = wid * 16 * 64;      // byte offset of this wave's staging slice

  f32x4 acc[4][4];
  const f32x4 z = {0.f, 0.f, 0.f, 0.f};
#pragma unroll
  for (int m = 0; m < 4; ++m)
#pragma unroll
    for (int n = 0; n < 4; ++n) acc[m][n] = z;

  const int fb = (lane & 15) * 64 + (lane >> 4) * 16;

  // prologue: stage k0 = 0 into buffer 0
  async16(gA,           (char*)As[0] + lofs);
  async16(gA + 64 * NN, (char*)As[0] + lofs + 64 * 64);
  async16(gB,           (char*)Bs[0] + lofs);
  async16(gB + 64 * NN, (char*)Bs[0] + lofs + 64 * 64);

  int cur = 0;
#pragma unroll 1
  for (int k0 = 0; k0 < NN - 32; k0 += 32) {
    // issue next tile's loads into the other buffer (stay in flight)
    const int nxt = cur ^ 1;
    async16(gA + k0 + 32,           (char*)As[nxt] + lofs);
    async16(gA + k0 + 32 + 64 * NN, (char*)As[nxt] + lofs + 64 * 64);
    async16(gB + k0 + 32,           (char*)Bs[nxt] + lofs);
    async16(gB + k0 + 32 + 64 * NN, (char*)Bs[nxt] + lofs + 64 * 64);
    // wait only for the CURRENT buffer's 4 loads (4 newer remain in flight)
    asm volatile("s_waitcnt vmcnt(4)" ::: "memory");
    __builtin_amdgcn_s_barrier();
    __builtin_amdgcn_sched_barrier(0);

    bf16x8 a[4], b[4];
#pragma unroll
    for (int m = 0; m < 4; ++m)
      a[m] = *(const bf16x8*)((const char*)As[cur] + (wr * 64 + m * 16) * 64 + fb);
#pragma unroll
    for (int n = 0; n < 4; ++n)
      b[n] = *(const bf16x8*)((const char*)Bs[cur] + (wc * 64 + n * 16) * 64 + fb);
#pragma unroll
    for (int m = 0; m < 4; ++m)
#pragma unroll
      for (int n = 0; n < 4; ++n)
        acc[m][n] = __builtin_amdgcn_mfma_f32_16x16x32_bf16(a[m], b[n], acc[m][n], 0, 0, 0);
    __builtin_amdgcn_s_barrier();
    __builtin_amdgcn_sched_barrier(0);
    cur ^= 1;
  }

  // epilogue K-step: drain and compute the final buffer
  asm volatile("s_waitcnt vmcnt(0)" ::: "memory");
  __builtin_amdgcn_s_barrier();
  __builtin_amdgcn_sched_barrier(0);
  {
    bf16x8 a[4], b[4];
#pragma unroll
    for (int m = 0; m < 4; ++m)
      a[m] = *(const bf16x8*)((const char*)As[cur] + (wr * 64 + m * 16) * 64 + fb);
#pragma unroll
    for (int n = 0; n < 4; ++n)
      b[n] = *(const bf16x8*)((const char*)Bs[cur] + (wc * 64 + n * 16) * 64 + fb);
#pragma unroll
    for (int m = 0; m < 4; ++m)
#pragma unroll
      for (int n = 0; n < 4; ++n)
        acc[m][n] = __builtin_amdgcn_mfma_f32_16x16x32_bf16(a[m], b[n], acc[m][n], 0, 0, 0);
  }

  const int fr = lane & 15;
  const int fq = lane >> 4;
#pragma unroll
  for (int m = 0; m < 4; ++m) {
    const int row0 = bM + wr * 64 + m * 16 + fq * 4;
#pragma unroll
    for (int n = 0; n < 4; ++n) {
      const int col = bN + wc * 64 + n * 16 + fr;
#pragma unroll
      for (int r = 0; r < 4; ++r)
        C[(size_t)(row0 + r) * NN + col] = acc[m][n][r];
    }
  }
  if (ti != tj) {
#pragma unroll
    for (int m = 0; m < 4; ++m) {
      const int colT = bM + wr * 64 + m * 16 + fq * 4;
#pragma unroll
      for (int n = 0; n < 4; ++n) {
        const int rowT = bN + wc * 64 + n * 16 + fr;
        *(f32x4*)(C + (size_t)rowT * NN + colT) = acc[m][n];
      }
    }
  }
}

// ---------------------------------------------------------------------------
extern "C" void kernel_launch(void* const* d_in, const int* in_sizes, int n_in,
                              void* d_out, int out_size, void* d_ws, size_t ws_size,
                              hipStream_t stream)
{
  const float* x = (const float*)d_in[0];   // [B,N,C]
  const float* W = (const float*)d_in[1];   // [2*H*C, C]
  float* logits = (float*)d_out;            // f32 logits, later final out
  char* ws = (char*)d_ws;

  __bf16* qk_hi = (__bf16*)(ws + ((size_t)0   << 20));   // 64 MiB
  __bf16* qk_lo = (__bf16*)(ws + ((size_t)64  << 20));   // 64 MiB
  __bf16* attnb = (__bf16*)(ws + ((size_t)0   << 20));   // 128 MiB (reuses qk)
  __bf16* x_hi  = (__bf16*)(ws + ((size_t)128 << 20));
  __bf16* x_lo  = (__bf16*)(ws + ((size_t)132 << 20));
  __bf16* W_hi  = (__bf16*)(ws + ((size_t)136 << 20));
  __bf16* W_lo  = (__bf16*)(ws + ((size_t)138 << 20));
  float*  se    = (float*)(ws + ((size_t)144 << 20));    // 32 MiB
  float*  cmask = (float*)(ws + ((size_t)176 << 20));    // 32 KiB
  float*  irs   = (float*)(ws + ((size_t)177 << 20));    // 256 KiB
  float*  isc   = (float*)(ws + ((size_t)178 << 20));    // 256 KiB
  float*  csp   = (float*)(ws + ((size_t)180 << 20));    // 4 MiB partials
  __bf16* Gb    = (__bf16*)(ws + ((size_t)192 << 20));   // 128 MiB

  // 0. split x and W into bf16 hi/lo (single launch)
  hipLaunchKernelGGL(split2_kernel, dim3((BB*NN*CC + OUTCH*CC) / 4 / 256), dim3(256), 0, stream,
                     x, W, x_hi, x_lo, W_hi, W_lo);

  // 1. qk = x @ W^T (split-bf16 MFMA)
  hipLaunchKernelGGL(xw_mfma_kernel, dim3(OUTCH/128, (BB*NN)/128, 1), dim3(256), 0, stream,
                     x_hi, x_lo, W_hi, W_lo, qk_hi, qk_lo);

  // 2. logits = scale * q @ k^T -> d_out (f32), bh-resident swizzle
  hipLaunchKernelGGL(qkt_mfma_kernel, dim3(64 * 64), dim3(256), 0, stream,
                     qk_hi, qk_lo, logits);

  // 3+4. softmax (f32 logits -> bf16 attn in ws) + head-sum
  hipLaunchKernelGGL(softmax_se_kernel, dim3(BB*NN), dim3(256), 0, stream,
                     logits, attnb, se);

  // 5. top-5 union -> column mask
  hipMemsetAsync(cmask, 0, (size_t)BB * NN * 4, stream);
  hipLaunchKernelGGL(topk_kernel, dim3(BB*NN), dim3(256), 0, stream, se, cmask);

  // 6+7. fused row sums + column partials, then finalize isc
  hipLaunchKernelGGL(cs_rs_kernel, dim3(16, BB*HH), dim3(256), 0, stream,
                     attnb, cmask, irs, csp);
  hipLaunchKernelGGL(cs_fin_kernel, dim3(BB*HH), dim3(256), 0, stream, csp, isc);

  // 8. Gb = bf16( e * inv_rs * isc )
  hipLaunchKernelGGL(g_kernel, dim3((BB*HH*NN*(long long)NN) / 4 / 256), dim3(256), 0, stream,
                     attnb, cmask, irs, isc, Gb);

  // 9. out = Gb @ Gb^T (symmetric MFMA, dbuf+counted-vmcnt, bh swizzle)
  hipLaunchKernelGGL(ggt_mfma_kernel, dim3(36 * 64), dim3(256), 0, stream,
                     Gb, logits);

  (void)in_sizes; (void)n_in; (void)out_size; (void)ws_size;
}

// Round 10
// 522.638 us; speedup vs baseline: 1.0913x; 1.0580x over previous
//
#include <hip/hip_runtime.h>
#include <hip/hip_bf16.h>
#include <cstdint>
#include <cstddef>

#define BB 8
#define HH 8
#define NN 1024
#define CC 256
#define YC 2048      // H*C (y plane width)

typedef __attribute__((ext_vector_type(8))) __bf16 bf16x8;
typedef __attribute__((ext_vector_type(4))) __bf16 bf16x4;
typedef __attribute__((ext_vector_type(4))) float f32x4;

// ---------------------------------------------------------------------------
__device__ inline void async16(const void* g, void* l)
{
  __builtin_amdgcn_global_load_lds(
      reinterpret_cast<const __attribute__((address_space(1))) unsigned int*>(
          reinterpret_cast<uintptr_t>(g)),
      reinterpret_cast<__attribute__((address_space(3))) unsigned int*>(
          reinterpret_cast<uintptr_t>(l)),
      16, 0, 0);
}

__device__ inline float waveMax(float v) {
#pragma unroll
  for (int o = 32; o > 0; o >>= 1) v = fmaxf(v, __shfl_xor(v, o, 64));
  return v;
}
__device__ inline float waveSum(float v) {
#pragma unroll
  for (int o = 32; o > 0; o >>= 1) v += __shfl_xor(v, o, 64);
  return v;
}

// ---------------------------------------------------------------------------
// split f32 -> (hi, lo) bf16 planes (x only)
// ---------------------------------------------------------------------------
__global__ __launch_bounds__(256) void split_kernel(const float* __restrict__ in,
                                                    __bf16* __restrict__ hi,
                                                    __bf16* __restrict__ lo)
{
  const int i = blockIdx.x * 256 + threadIdx.x;
  const float4 v = ((const float4*)in)[i];
  bf16x4 h, l;
  h.x = (__bf16)v.x; l.x = (__bf16)(v.x - (float)h.x);
  h.y = (__bf16)v.y; l.y = (__bf16)(v.y - (float)h.y);
  h.z = (__bf16)v.z; l.z = (__bf16)(v.z - (float)h.z);
  h.w = (__bf16)v.w; l.w = (__bf16)(v.w - (float)h.w);
  ((bf16x4*)hi)[i] = h;
  ((bf16x4*)lo)[i] = l;
}

// ---------------------------------------------------------------------------
// W^T transpose + split: T[z][c][i] = W[z*256 + i][c] as bf16 hi/lo,
// z = qk*8 + h (W row block (qk*2048 + h*256)). Grid (4,4,16), 64x64 tiles.
// ---------------------------------------------------------------------------
__global__ __launch_bounds__(256) void wt_split_kernel(const float* __restrict__ W,
                                                       __bf16* __restrict__ Th,
                                                       __bf16* __restrict__ Tl)
{
  const int z = blockIdx.z;
  const float* Wb = W + ((size_t)z << 16);
  __shared__ float t[64][65];
  const int i0 = blockIdx.x * 64, c0 = blockIdx.y * 64;
  const int tr = threadIdx.x >> 6;      // 0..3
  const int tc = threadIdx.x & 63;
#pragma unroll
  for (int rr = 0; rr < 64; rr += 4)
    t[rr + tr][tc] = Wb[(size_t)(i0 + rr + tr) * 256 + c0 + tc];
  __syncthreads();
  __bf16* Thb = Th + ((size_t)z << 16);
  __bf16* Tlb = Tl + ((size_t)z << 16);
#pragma unroll
  for (int cc = 0; cc < 64; cc += 4) {
    const int c = cc + tr, i = tc;
    const float v = t[i][c];
    const __bf16 h = (__bf16)v;
    Thb[(size_t)(c0 + c) * 256 + i0 + i] = h;
    Tlb[(size_t)(c0 + c) * 256 + i0 + i] = (__bf16)(v - (float)h);
  }
}

// ---------------------------------------------------------------------------
// P[h] = WkT[h] @ WqT[h]^T  (so P[h*256+c'][c] = sum_i Wk[i,c']*Wq[i,c]).
// Split-bf16 3-MFMA, output hi/lo. Grid (2,2,8), 128x128 tiles, K=256.
// ---------------------------------------------------------------------------
__global__ __launch_bounds__(256) void pp_mfma_kernel(
    const __bf16* __restrict__ Th, const __bf16* __restrict__ Tl,
    __bf16* __restrict__ Phi, __bf16* __restrict__ Plo)
{
  const int h = blockIdx.z;
  const __bf16* Ah = Th + ((size_t)(8 + h) << 16);   // WkT
  const __bf16* Al = Tl + ((size_t)(8 + h) << 16);
  const __bf16* Bh = Th + ((size_t)h << 16);         // WqT
  const __bf16* Bl = Tl + ((size_t)h << 16);

  __shared__ __bf16 AsH[128 * 32], AsL[128 * 32], BsH[128 * 32], BsL[128 * 32];

  const int tid = threadIdx.x, lane = tid & 63, wid = tid >> 6;
  const int wr = wid >> 1, wc = wid & 1;
  const int bM = blockIdx.y * 128, bN = blockIdx.x * 128;

  const int srow = wid * 16 + (lane >> 2);
  const int scol = (lane & 3) * 8;
  const __bf16* gAh = Ah + (size_t)(bM + srow) * CC + scol;
  const __bf16* gAl = Al + (size_t)(bM + srow) * CC + scol;
  const __bf16* gBh = Bh + (size_t)(bN + srow) * CC + scol;
  const __bf16* gBl = Bl + (size_t)(bN + srow) * CC + scol;
  char* lAh = (char*)AsH + wid * 16 * 64;
  char* lAl = (char*)AsL + wid * 16 * 64;
  char* lBh = (char*)BsH + wid * 16 * 64;
  char* lBl = (char*)BsL + wid * 16 * 64;

  f32x4 acc[4][4];
  const f32x4 z4 = {0.f, 0.f, 0.f, 0.f};
#pragma unroll
  for (int m = 0; m < 4; ++m)
#pragma unroll
    for (int n = 0; n < 4; ++n) acc[m][n] = z4;

  for (int k0 = 0; k0 < CC; k0 += 32) {
    async16(gAh + k0, lAh); async16(gAh + k0 + 64 * CC, lAh + 64 * 64);
    async16(gAl + k0, lAl); async16(gAl + k0 + 64 * CC, lAl + 64 * 64);
    async16(gBh + k0, lBh); async16(gBh + k0 + 64 * CC, lBh + 64 * 64);
    async16(gBl + k0, lBl); async16(gBl + k0 + 64 * CC, lBl + 64 * 64);
    __syncthreads();

    bf16x8 ah[4], al[4], bh_[4], bl_[4];
    const int fb = (lane & 15) * 64 + (lane >> 4) * 16;
#pragma unroll
    for (int m = 0; m < 4; ++m) {
      ah[m] = *(const bf16x8*)((const char*)AsH + (wr * 64 + m * 16) * 64 + fb);
      al[m] = *(const bf16x8*)((const char*)AsL + (wr * 64 + m * 16) * 64 + fb);
    }
#pragma unroll
    for (int n = 0; n < 4; ++n) {
      bh_[n] = *(const bf16x8*)((const char*)BsH + (wc * 64 + n * 16) * 64 + fb);
      bl_[n] = *(const bf16x8*)((const char*)BsL + (wc * 64 + n * 16) * 64 + fb);
    }
#pragma unroll
    for (int m = 0; m < 4; ++m)
#pragma unroll
      for (int n = 0; n < 4; ++n) {
        acc[m][n] = __builtin_amdgcn_mfma_f32_16x16x32_bf16(al[m], bh_[n], acc[m][n], 0, 0, 0);
        acc[m][n] = __builtin_amdgcn_mfma_f32_16x16x32_bf16(ah[m], bl_[n], acc[m][n], 0, 0, 0);
        acc[m][n] = __builtin_amdgcn_mfma_f32_16x16x32_bf16(ah[m], bh_[n], acc[m][n], 0, 0, 0);
      }
    __syncthreads();
  }

  const int fr = lane & 15;
  const int fq = lane >> 4;
#pragma unroll
  for (int m = 0; m < 4; ++m) {
    const int row0 = h * 256 + bM + wr * 64 + m * 16 + fq * 4;
#pragma unroll
    for (int n = 0; n < 4; ++n) {
      const int col = bN + wc * 64 + n * 16 + fr;
#pragma unroll
      for (int r = 0; r < 4; ++r) {
        const float v = acc[m][n][r];
        const __bf16 hh = (__bf16)v;
        Phi[(size_t)(row0 + r) * CC + col] = hh;
        Plo[(size_t)(row0 + r) * CC + col] = (__bf16)(v - (float)hh);
      }
    }
  }
}

// ---------------------------------------------------------------------------
// y = x @ P^T : [8192, 2048], split-bf16 3-MFMA, output hi/lo planes.
// ---------------------------------------------------------------------------
__global__ __launch_bounds__(256) void y_mfma_kernel(
    const __bf16* __restrict__ Ah, const __bf16* __restrict__ Al,
    const __bf16* __restrict__ Bh, const __bf16* __restrict__ Bl,
    __bf16* __restrict__ Chi, __bf16* __restrict__ Clo)
{
  __shared__ __bf16 AsH[128 * 32], AsL[128 * 32], BsH[128 * 32], BsL[128 * 32];

  const int tid = threadIdx.x, lane = tid & 63, wid = tid >> 6;
  const int wr = wid >> 1, wc = wid & 1;
  const int bM = blockIdx.y * 128, bN = blockIdx.x * 128;

  const int srow = wid * 16 + (lane >> 2);
  const int scol = (lane & 3) * 8;
  const __bf16* gAh = Ah + (size_t)(bM + srow) * CC + scol;
  const __bf16* gAl = Al + (size_t)(bM + srow) * CC + scol;
  const __bf16* gBh = Bh + (size_t)(bN + srow) * CC + scol;
  const __bf16* gBl = Bl + (size_t)(bN + srow) * CC + scol;
  char* lAh = (char*)AsH + wid * 16 * 64;
  char* lAl = (char*)AsL + wid * 16 * 64;
  char* lBh = (char*)BsH + wid * 16 * 64;
  char* lBl = (char*)BsL + wid * 16 * 64;

  f32x4 acc[4][4];
  const f32x4 z = {0.f, 0.f, 0.f, 0.f};
#pragma unroll
  for (int m = 0; m < 4; ++m)
#pragma unroll
    for (int n = 0; n < 4; ++n) acc[m][n] = z;

  for (int k0 = 0; k0 < CC; k0 += 32) {
    async16(gAh + k0, lAh); async16(gAh + k0 + 64 * CC, lAh + 64 * 64);
    async16(gAl + k0, lAl); async16(gAl + k0 + 64 * CC, lAl + 64 * 64);
    async16(gBh + k0, lBh); async16(gBh + k0 + 64 * CC, lBh + 64 * 64);
    async16(gBl + k0, lBl); async16(gBl + k0 + 64 * CC, lBl + 64 * 64);
    __syncthreads();

    bf16x8 ah[4], al[4], bh_[4], bl_[4];
    const int fb = (lane & 15) * 64 + (lane >> 4) * 16;
#pragma unroll
    for (int m = 0; m < 4; ++m) {
      ah[m] = *(const bf16x8*)((const char*)AsH + (wr * 64 + m * 16) * 64 + fb);
      al[m] = *(const bf16x8*)((const char*)AsL + (wr * 64 + m * 16) * 64 + fb);
    }
#pragma unroll
    for (int n = 0; n < 4; ++n) {
      bh_[n] = *(const bf16x8*)((const char*)BsH + (wc * 64 + n * 16) * 64 + fb);
      bl_[n] = *(const bf16x8*)((const char*)BsL + (wc * 64 + n * 16) * 64 + fb);
    }
#pragma unroll
    for (int m = 0; m < 4; ++m)
#pragma unroll
      for (int n = 0; n < 4; ++n) {
        acc[m][n] = __builtin_amdgcn_mfma_f32_16x16x32_bf16(al[m], bh_[n], acc[m][n], 0, 0, 0);
        acc[m][n] = __builtin_amdgcn_mfma_f32_16x16x32_bf16(ah[m], bl_[n], acc[m][n], 0, 0, 0);
        acc[m][n] = __builtin_amdgcn_mfma_f32_16x16x32_bf16(ah[m], bh_[n], acc[m][n], 0, 0, 0);
      }
    __syncthreads();
  }

  const int fr = lane & 15;
  const int fq = lane >> 4;
#pragma unroll
  for (int m = 0; m < 4; ++m) {
    const int row0 = bM + wr * 64 + m * 16 + fq * 4;
#pragma unroll
    for (int n = 0; n < 4; ++n) {
      const int col = bN + wc * 64 + n * 16 + fr;
#pragma unroll
      for (int r = 0; r < 4; ++r) {
        const float v = acc[m][n][r];
        const __bf16 h = (__bf16)v;
        Chi[(size_t)(row0 + r) * YC + col] = h;
        Clo[(size_t)(row0 + r) * YC + col] = (__bf16)(v - (float)h);
      }
    }
  }
}

// ---------------------------------------------------------------------------
// logits[b,h] = (1/16) * y_bh @ x_b^T -> f32.  A = y (lda 2048, head off 256),
// B = x (lda 256). bh-resident XCD swizzle: f = (bh%8) + 8*((bh/8)*64 + tile)
// ---------------------------------------------------------------------------
__global__ __launch_bounds__(256) void qkt_mfma_kernel(
    const __bf16* __restrict__ Yh, const __bf16* __restrict__ Yl,
    const __bf16* __restrict__ Xh, const __bf16* __restrict__ Xl,
    float* __restrict__ outall)
{
  const int f = blockIdx.x;
  const int xcd = f & 7;
  const int g = f >> 3;
  const int bh = xcd + 8 * (g >> 6);
  const int tile = g & 63;
  const int b = bh >> 3, h = bh & 7;
  const size_t aoff = (size_t)b * NN * YC + (size_t)h * CC;
  const size_t boff = (size_t)b * NN * CC;
  float* C = outall + ((size_t)bh << 20);

  __shared__ __bf16 AsH[128 * 32], AsL[128 * 32], BsH[128 * 32], BsL[128 * 32];

  const int tid = threadIdx.x, lane = tid & 63, wid = tid >> 6;
  const int wr = wid >> 1, wc = wid & 1;
  const int bM = (tile >> 3) * 128, bN = (tile & 7) * 128;

  const int srow = wid * 16 + (lane >> 2);
  const int scol = (lane & 3) * 8;
  const __bf16* gAh = Yh + aoff + (size_t)(bM + srow) * YC + scol;
  const __bf16* gAl = Yl + aoff + (size_t)(bM + srow) * YC + scol;
  const __bf16* gBh = Xh + boff + (size_t)(bN + srow) * CC + scol;
  const __bf16* gBl = Xl + boff + (size_t)(bN + srow) * CC + scol;
  char* lAh = (char*)AsH + wid * 16 * 64;
  char* lAl = (char*)AsL + wid * 16 * 64;
  char* lBh = (char*)BsH + wid * 16 * 64;
  char* lBl = (char*)BsL + wid * 16 * 64;

  f32x4 acc[4][4];
  const f32x4 z = {0.f, 0.f, 0.f, 0.f};
#pragma unroll
  for (int m = 0; m < 4; ++m)
#pragma unroll
    for (int n = 0; n < 4; ++n) acc[m][n] = z;

  for (int k0 = 0; k0 < CC; k0 += 32) {
    async16(gAh + k0, lAh); async16(gAh + k0 + (size_t)64 * YC, lAh + 64 * 64);
    async16(gAl + k0, lAl); async16(gAl + k0 + (size_t)64 * YC, lAl + 64 * 64);
    async16(gBh + k0, lBh); async16(gBh + k0 + (size_t)64 * CC, lBh + 64 * 64);
    async16(gBl + k0, lBl); async16(gBl + k0 + (size_t)64 * CC, lBl + 64 * 64);
    __syncthreads();

    bf16x8 ah[4], al[4], bh_[4], bl_[4];
    const int fb = (lane & 15) * 64 + (lane >> 4) * 16;
#pragma unroll
    for (int m = 0; m < 4; ++m) {
      ah[m] = *(const bf16x8*)((const char*)AsH + (wr * 64 + m * 16) * 64 + fb);
      al[m] = *(const bf16x8*)((const char*)AsL + (wr * 64 + m * 16) * 64 + fb);
    }
#pragma unroll
    for (int n = 0; n < 4; ++n) {
      bh_[n] = *(const bf16x8*)((const char*)BsH + (wc * 64 + n * 16) * 64 + fb);
      bl_[n] = *(const bf16x8*)((const char*)BsL + (wc * 64 + n * 16) * 64 + fb);
    }
#pragma unroll
    for (int m = 0; m < 4; ++m)
#pragma unroll
      for (int n = 0; n < 4; ++n) {
        acc[m][n] = __builtin_amdgcn_mfma_f32_16x16x32_bf16(al[m], bh_[n], acc[m][n], 0, 0, 0);
        acc[m][n] = __builtin_amdgcn_mfma_f32_16x16x32_bf16(ah[m], bl_[n], acc[m][n], 0, 0, 0);
        acc[m][n] = __builtin_amdgcn_mfma_f32_16x16x32_bf16(ah[m], bh_[n], acc[m][n], 0, 0, 0);
      }
    __syncthreads();
  }

  const int fr = lane & 15;
  const int fq = lane >> 4;
#pragma unroll
  for (int m = 0; m < 4; ++m) {
    const int row0 = bM + wr * 64 + m * 16 + fq * 4;
#pragma unroll
    for (int n = 0; n < 4; ++n) {
      const int col = bN + wc * 64 + n * 16 + fr;
#pragma unroll
      for (int r = 0; r < 4; ++r)
        C[(size_t)(row0 + r) * NN + col] = acc[m][n][r] * 0.0625f;
    }
  }
}

// ---------------------------------------------------------------------------
// Fused softmax + head-sum. f32 logits in, bf16 attn -> ws (contig).
// ---------------------------------------------------------------------------
__global__ __launch_bounds__(256) void softmax_se_kernel(const float* __restrict__ logits,
                                                         __bf16* __restrict__ attnb,
                                                         float* __restrict__ se)
{
  const int bn = blockIdx.x;
  const int b = bn >> 10;
  const int n = bn & 1023;
  const int t = threadIdx.x;
  const int lane = t & 63, wv = t >> 6;
  __shared__ float wred[4];
  float4 acc = make_float4(0.f, 0.f, 0.f, 0.f);

#pragma unroll 1
  for (int h = 0; h < HH; ++h) {
    const size_t rowbase = (((size_t)(b * HH + h) << 10) + n) << 10;
    const float* ar = logits + rowbase;
    __bf16* arb = attnb + rowbase;
    float4 x = *(const float4*)(ar + (t << 2));
    float mx = waveMax(fmaxf(fmaxf(x.x, x.y), fmaxf(x.z, x.w)));
    if (lane == 0) wred[wv] = mx;
    __syncthreads();
    const float M = fmaxf(fmaxf(wred[0], wred[1]), fmaxf(wred[2], wred[3]));
    __syncthreads();

    float e0 = expf(x.x - M), e1 = expf(x.y - M), e2 = expf(x.z - M), e3 = expf(x.w - M);
    float s = waveSum(e0 + e1 + e2 + e3);
    if (lane == 0) wred[wv] = s;
    __syncthreads();
    const float inv = 1.0f / (wred[0] + wred[1] + wred[2] + wred[3]);

    const float o0 = e0 * inv, o1 = e1 * inv, o2 = e2 * inv, o3 = e3 * inv;
    bf16x4 ob; ob.x = (__bf16)o0; ob.y = (__bf16)o1; ob.z = (__bf16)o2; ob.w = (__bf16)o3;
    *(bf16x4*)(arb + (t << 2)) = ob;
    acc.x += o0; acc.y += o1; acc.z += o2; acc.w += o3;
    __syncthreads();
  }
  *(float4*)(se + (size_t)bn * NN + (t << 2)) = acc;
}

// ---------------------------------------------------------------------------
// Top-5 per row of sum_edge; colmask[b, idx] = 1 for each winner.
// ---------------------------------------------------------------------------
__global__ __launch_bounds__(256) void topk_kernel(const float* __restrict__ se,
                                                   float* __restrict__ colmask)
{
  const int bn = blockIdx.x;
  const int b = bn >> 10;
  const int t = threadIdx.x;
  __shared__ float vals[NN];
  __shared__ unsigned long long red[256];
  const float* rowp = se + (size_t)bn * NN;
  for (int i = t; i < NN; i += 256) vals[i] = rowp[i];
  __syncthreads();

  for (int it = 0; it < 5; ++it) {
    unsigned long long best = 0ull;
    for (int i = t; i < NN; i += 256) {
      const float v = vals[i];
      if (v >= 0.f) {
        unsigned long long key =
            ((unsigned long long)__float_as_uint(v) << 32) | (unsigned)(NN - 1 - i);
        if (key > best) best = key;
      }
    }
    red[t] = best; __syncthreads();
    for (int s = 128; s > 0; s >>= 1) {
      if (t < s) red[t] = red[t] > red[t+s] ? red[t] : red[t+s];
      __syncthreads();
    }
    if (t == 0) {
      const int idx = NN - 1 - (int)(red[0] & 0xFFFFFFFFull);
      colmask[b * NN + idx] = 1.0f;
      vals[idx] = -1.0f;
    }
    __syncthreads();
  }
}

// ---------------------------------------------------------------------------
// Fused rs+cs stage 1. Grid (16, B*H).
// ---------------------------------------------------------------------------
__global__ __launch_bounds__(256) void cs_rs_kernel(const __bf16* __restrict__ attnb,
                                                    const float* __restrict__ colmask,
                                                    float* __restrict__ inv_rs,
                                                    float* __restrict__ part)
{
  const int bh = blockIdx.y;
  const int b = bh >> 3;
  const int chunk = blockIdx.x;
  const int t = threadIdx.x, lane = t & 63, wv = t >> 6;
  const __bf16* ab = attnb + ((size_t)bh << 20);
  const float* cm = colmask + b * NN;
  const int c0 = lane * 16;

  float cmv[16];
#pragma unroll
  for (int q = 0; q < 4; ++q) {
    const float4 c4 = *(const float4*)(cm + c0 + q * 4);
    cmv[q*4+0] = c4.x; cmv[q*4+1] = c4.y; cmv[q*4+2] = c4.z; cmv[q*4+3] = c4.w;
  }

  float a[16];
#pragma unroll
  for (int j = 0; j < 16; ++j) a[j] = 0.f;

  const int nbase = chunk * 64 + wv * 16;
#pragma unroll 1
  for (int r = 0; r < 16; ++r) {
    const int n = nbase + r;
    const __bf16* rowp = ab + ((size_t)n << 10) + c0;
    const bf16x8 v0 = *(const bf16x8*)(rowp);
    const bf16x8 v1 = *(const bf16x8*)(rowp + 8);
    float e[16];
    float rsum = 0.f;
#pragma unroll
    for (int j = 0; j < 8; ++j) {
      const float val = ((cmv[j] != 0.f) || (c0 + j == n)) ? (float)v0[j] : 0.f;
      e[j] = val; rsum += val;
    }
#pragma unroll
    for (int j = 0; j < 8; ++j) {
      const float val = ((cmv[8+j] != 0.f) || (c0 + 8 + j == n)) ? (float)v1[j] : 0.f;
      e[8+j] = val; rsum += val;
    }
    rsum = waveSum(rsum);
    const float ir = 1.0f / (rsum + 1e-16f);
    if (lane == 0) inv_rs[bh * NN + n] = ir;
#pragma unroll
    for (int j = 0; j < 16; ++j) a[j] += e[j] * ir;
  }

  __shared__ float l[4][NN];
#pragma unroll
  for (int j = 0; j < 16; ++j) l[wv][c0 + j] = a[j];
  __syncthreads();
  const int m0 = t << 2;
  float4 o;
  o.x = l[0][m0+0] + l[1][m0+0] + l[2][m0+0] + l[3][m0+0];
  o.y = l[0][m0+1] + l[1][m0+1] + l[2][m0+1] + l[3][m0+1];
  o.z = l[0][m0+2] + l[1][m0+2] + l[2][m0+2] + l[3][m0+2];
  o.w = l[0][m0+3] + l[1][m0+3] + l[2][m0+3] + l[3][m0+3];
  *(float4*)(part + (((size_t)chunk * (BB*HH) + bh) << 10) + m0) = o;
}

// ---------------------------------------------------------------------------
__global__ __launch_bounds__(256) void cs_fin_kernel(const float* __restrict__ part,
                                                     float* __restrict__ isc)
{
  const int bh = blockIdx.x;
  const int m0 = threadIdx.x << 2;
  float a0 = 0.f, a1 = 0.f, a2 = 0.f, a3 = 0.f;
#pragma unroll
  for (int c = 0; c < 16; ++c) {
    const float4 p = *(const float4*)(part + (((size_t)c * (BB*HH) + bh) << 10) + m0);
    a0 += p.x; a1 += p.y; a2 += p.z; a3 += p.w;
  }
  float4 o;
  o.x = 1.0f / sqrtf(a0 + 1e-16f);
  o.y = 1.0f / sqrtf(a1 + 1e-16f);
  o.z = 1.0f / sqrtf(a2 + 1e-16f);
  o.w = 1.0f / sqrtf(a3 + 1e-16f);
  *(float4*)(isc + ((size_t)bh << 10) + m0) = o;
}

// ---------------------------------------------------------------------------
__global__ __launch_bounds__(256) void g_kernel(const __bf16* __restrict__ attnb,
                                                const float* __restrict__ colmask,
                                                const float* __restrict__ inv_rs,
                                                const float* __restrict__ isc,
                                                __bf16* __restrict__ Gb)
{
  const size_t idx = ((size_t)blockIdx.x * 256 + threadIdx.x) << 2;
  const size_t row = idx >> 10;
  const int m = (int)(idx & 1023);
  const int n = (int)(row & 1023);
  const int bh = (int)(row >> 10);
  const int b = bh >> 3;
  const bf16x4 vb = *(const bf16x4*)(attnb + idx);
  const float4 c = *(const float4*)(colmask + b * NN + m);
  const float4 s = *(const float4*)(isc + ((size_t)bh << 10) + m);
  const float ir = inv_rs[row];
  bf16x4 o;
  o.x = (__bf16)((((c.x != 0.f) || (m + 0 == n)) ? (float)vb.x : 0.f) * ir * s.x);
  o.y = (__bf16)((((c.y != 0.f) || (m + 1 == n)) ? (float)vb.y : 0.f) * ir * s.y);
  o.z = (__bf16)((((c.z != 0.f) || (m + 2 == n)) ? (float)vb.z : 0.f) * ir * s.z);
  o.w = (__bf16)((((c.w != 0.f) || (m + 3 == n)) ? (float)vb.w : 0.f) * ir * s.w);
  *(bf16x4*)(Gb + idx) = o;
}

// ---------------------------------------------------------------------------
// out[b,h] = Gb @ Gb^T (symmetric, dbuf + counted vmcnt(4), XCD swizzle).
// ---------------------------------------------------------------------------
__global__ __launch_bounds__(256) void ggt_mfma_kernel(const __bf16* __restrict__ Gball,
                                                       float* __restrict__ outall)
{
  const int f = blockIdx.x;
  const int xcd = f & 7;
  const int g = f >> 3;
  const int bh = xcd + 8 * (g / 36);
  int tt = g % 36;

  const __bf16* A = Gball + ((size_t)bh << 20);
  float* C = outall + ((size_t)bh << 20);

  int ti = 0;
#pragma unroll
  for (int r = 0; r < 8; ++r) {
    const int len = 8 - r;
    if (tt < len) { ti = r; break; }
    tt -= len;
  }
  const int tj = ti + tt;

  __shared__ __bf16 As[2][128 * 32];
  __shared__ __bf16 Bs[2][128 * 32];

  const int tid  = threadIdx.x;
  const int lane = tid & 63;
  const int wid  = tid >> 6;
  const int wr   = wid >> 1;
  const int wc   = wid & 1;
  const int bM   = ti * 128;
  const int bN   = tj * 128;

  const int srow = wid * 16 + (lane >> 2);
  const int scol = (lane & 3) * 8;
  const __bf16* gA = A + (size_t)(bM + srow) * NN + scol;
  const __bf16* gB = A + (size_t)(bN + srow) * NN + scol;
  const int lofs = wid * 16 * 64;

  f32x4 acc[4][4];
  const f32x4 z = {0.f, 0.f, 0.f, 0.f};
#pragma unroll
  for (int m = 0; m < 4; ++m)
#pragma unroll
    for (int n = 0; n < 4; ++n) acc[m][n] = z;

  const int fb = (lane & 15) * 64 + (lane >> 4) * 16;

  async16(gA,           (char*)As[0] + lofs);
  async16(gA + 64 * NN, (char*)As[0] + lofs + 64 * 64);
  async16(gB,           (char*)Bs[0] + lofs);
  async16(gB + 64 * NN, (char*)Bs[0] + lofs + 64 * 64);

  int cur = 0;
#pragma unroll 1
  for (int k0 = 0; k0 < NN - 32; k0 += 32) {
    const int nxt = cur ^ 1;
    async16(gA + k0 + 32,           (char*)As[nxt] + lofs);
    async16(gA + k0 + 32 + 64 * NN, (char*)As[nxt] + lofs + 64 * 64);
    async16(gB + k0 + 32,           (char*)Bs[nxt] + lofs);
    async16(gB + k0 + 32 + 64 * NN, (char*)Bs[nxt] + lofs + 64 * 64);
    asm volatile("s_waitcnt vmcnt(4)" ::: "memory");
    __builtin_amdgcn_s_barrier();
    __builtin_amdgcn_sched_barrier(0);

    bf16x8 a[4], b[4];
#pragma unroll
    for (int m = 0; m < 4; ++m)
      a[m] = *(const bf16x8*)((const char*)As[cur] + (wr * 64 + m * 16) * 64 + fb);
#pragma unroll
    for (int n = 0; n < 4; ++n)
      b[n] = *(const bf16x8*)((const char*)Bs[cur] + (wc * 64 + n * 16) * 64 + fb);
#pragma unroll
    for (int m = 0; m < 4; ++m)
#pragma unroll
      for (int n = 0; n < 4; ++n)
        acc[m][n] = __builtin_amdgcn_mfma_f32_16x16x32_bf16(a[m], b[n], acc[m][n], 0, 0, 0);
    __builtin_amdgcn_s_barrier();
    __builtin_amdgcn_sched_barrier(0);
    cur ^= 1;
  }

  asm volatile("s_waitcnt vmcnt(0)" ::: "memory");
  __builtin_amdgcn_s_barrier();
  __builtin_amdgcn_sched_barrier(0);
  {
    bf16x8 a[4], b[4];
#pragma unroll
    for (int m = 0; m < 4; ++m)
      a[m] = *(const bf16x8*)((const char*)As[cur] + (wr * 64 + m * 16) * 64 + fb);
#pragma unroll
    for (int n = 0; n < 4; ++n)
      b[n] = *(const bf16x8*)((const char*)Bs[cur] + (wc * 64 + n * 16) * 64 + fb);
#pragma unroll
    for (int m = 0; m < 4; ++m)
#pragma unroll
      for (int n = 0; n < 4; ++n)
        acc[m][n] = __builtin_amdgcn_mfma_f32_16x16x32_bf16(a[m], b[n], acc[m][n], 0, 0, 0);
  }

  const int fr = lane & 15;
  const int fq = lane >> 4;
#pragma unroll
  for (int m = 0; m < 4; ++m) {
    const int row0 = bM + wr * 64 + m * 16 + fq * 4;
#pragma unroll
    for (int n = 0; n < 4; ++n) {
      const int col = bN + wc * 64 + n * 16 + fr;
#pragma unroll
      for (int r = 0; r < 4; ++r)
        C[(size_t)(row0 + r) * NN + col] = acc[m][n][r];
    }
  }
  if (ti != tj) {
#pragma unroll
    for (int m = 0; m < 4; ++m) {
      const int colT = bM + wr * 64 + m * 16 + fq * 4;
#pragma unroll
      for (int n = 0; n < 4; ++n) {
        const int rowT = bN + wc * 64 + n * 16 + fr;
        *(f32x4*)(C + (size_t)rowT * NN + colT) = acc[m][n];
      }
    }
  }
}

// ---------------------------------------------------------------------------
extern "C" void kernel_launch(void* const* d_in, const int* in_sizes, int n_in,
                              void* d_out, int out_size, void* d_ws, size_t ws_size,
                              hipStream_t stream)
{
  const float* x = (const float*)d_in[0];   // [B,N,C]
  const float* W = (const float*)d_in[1];   // [2*H*C, C]
  float* logits = (float*)d_out;
  char* ws = (char*)d_ws;

  __bf16* y_hi  = (__bf16*)(ws + ((size_t)0   << 20));   // 32 MiB [8192,2048]
  __bf16* y_lo  = (__bf16*)(ws + ((size_t)32  << 20));   // 32 MiB
  __bf16* attnb = (__bf16*)(ws + ((size_t)0   << 20));   // 128 MiB (reuses y after qkt)
  __bf16* x_hi  = (__bf16*)(ws + ((size_t)128 << 20));   // 4 MiB
  __bf16* x_lo  = (__bf16*)(ws + ((size_t)132 << 20));   // 4 MiB
  __bf16* T_hi  = (__bf16*)(ws + ((size_t)136 << 20));   // 2 MiB  [16,256,256]
  __bf16* T_lo  = (__bf16*)(ws + ((size_t)138 << 20));   // 2 MiB
  __bf16* P_hi  = (__bf16*)(ws + ((size_t)140 << 20));   // 1 MiB  [2048,256]
  __bf16* P_lo  = (__bf16*)(ws + ((size_t)142 << 20));   // 1 MiB
  float*  se    = (float*)(ws + ((size_t)144 << 20));    // 32 MiB
  float*  cmask = (float*)(ws + ((size_t)176 << 20));
  float*  irs   = (float*)(ws + ((size_t)177 << 20));
  float*  isc   = (float*)(ws + ((size_t)178 << 20));
  float*  csp   = (float*)(ws + ((size_t)180 << 20));    // 4 MiB
  __bf16* Gb    = (__bf16*)(ws + ((size_t)192 << 20));   // 128 MiB

  // 0a. split x -> hi/lo
  hipLaunchKernelGGL(split_kernel, dim3(BB*NN*CC/4/256), dim3(256), 0, stream,
                     x, x_hi, x_lo);
  // 0b. W^T transpose + split (WqT z=0..7, WkT z=8..15)
  hipLaunchKernelGGL(wt_split_kernel, dim3(4, 4, 16), dim3(256), 0, stream,
                     W, T_hi, T_lo);
  // 0c. P[h] = WkT @ WqT^T (hi/lo out)
  hipLaunchKernelGGL(pp_mfma_kernel, dim3(2, 2, 8), dim3(256), 0, stream,
                     T_hi, T_lo, P_hi, P_lo);

  // 1. y = x @ P^T : [8192, 2048] hi/lo
  hipLaunchKernelGGL(y_mfma_kernel, dim3(YC/128, (BB*NN)/128, 1), dim3(256), 0, stream,
                     x_hi, x_lo, P_hi, P_lo, y_hi, y_lo);

  // 2. logits = (1/16) y @ x^T -> d_out (f32), bh-resident swizzle
  hipLaunchKernelGGL(qkt_mfma_kernel, dim3(64 * 64), dim3(256), 0, stream,
                     y_hi, y_lo, x_hi, x_lo, logits);

  // 3+4. softmax (f32 -> bf16 attn in ws) + head-sum
  hipLaunchKernelGGL(softmax_se_kernel, dim3(BB*NN), dim3(256), 0, stream,
                     logits, attnb, se);

  // 5. top-5 union -> column mask
  hipMemsetAsync(cmask, 0, (size_t)BB * NN * 4, stream);
  hipLaunchKernelGGL(topk_kernel, dim3(BB*NN), dim3(256), 0, stream, se, cmask);

  // 6+7. fused row sums + column partials, then finalize isc
  hipLaunchKernelGGL(cs_rs_kernel, dim3(16, BB*HH), dim3(256), 0, stream,
                     attnb, cmask, irs, csp);
  hipLaunchKernelGGL(cs_fin_kernel, dim3(BB*HH), dim3(256), 0, stream, csp, isc);

  // 8. Gb = bf16( e * inv_rs * isc )
  hipLaunchKernelGGL(g_kernel, dim3((BB*HH*NN*(long long)NN) / 4 / 256), dim3(256), 0, stream,
                     attnb, cmask, irs, isc, Gb);

  // 9. out = Gb @ Gb^T (symmetric MFMA, dbuf+counted-vmcnt, bh swizzle)
  hipLaunchKernelGGL(ggt_mfma_kernel, dim3(36 * 64), dim3(256), 0, stream,
                     Gb, logits);

  (void)in_sizes; (void)n_in; (void)out_size; (void)ws_size;
}

// Round 11
// 508.325 us; speedup vs baseline: 1.1220x; 1.0282x over previous
//
#include <hip/hip_runtime.h>
#include <hip/hip_bf16.h>
#include <cstdint>
#include <cstddef>

#define BB 8
#define HH 8
#define NN 1024
#define CC 256
#define YC 2048      // H*C (y plane width)

typedef __attribute__((ext_vector_type(8))) __bf16 bf16x8;
typedef __attribute__((ext_vector_type(4))) __bf16 bf16x4;
typedef __attribute__((ext_vector_type(4))) float f32x4;

// ---------------------------------------------------------------------------
__device__ inline void async16(const void* g, void* l)
{
  __builtin_amdgcn_global_load_lds(
      reinterpret_cast<const __attribute__((address_space(1))) unsigned int*>(
          reinterpret_cast<uintptr_t>(g)),
      reinterpret_cast<__attribute__((address_space(3))) unsigned int*>(
          reinterpret_cast<uintptr_t>(l)),
      16, 0, 0);
}

__device__ inline float waveMax(float v) {
#pragma unroll
  for (int o = 32; o > 0; o >>= 1) v = fmaxf(v, __shfl_xor(v, o, 64));
  return v;
}
__device__ inline float waveSum(float v) {
#pragma unroll
  for (int o = 32; o > 0; o >>= 1) v += __shfl_xor(v, o, 64);
  return v;
}

// ---------------------------------------------------------------------------
// split f32 -> (hi, lo) bf16 planes (x only)
// ---------------------------------------------------------------------------
__global__ __launch_bounds__(256) void split_kernel(const float* __restrict__ in,
                                                    __bf16* __restrict__ hi,
                                                    __bf16* __restrict__ lo)
{
  const int i = blockIdx.x * 256 + threadIdx.x;
  const float4 v = ((const float4*)in)[i];
  bf16x4 h, l;
  h.x = (__bf16)v.x; l.x = (__bf16)(v.x - (float)h.x);
  h.y = (__bf16)v.y; l.y = (__bf16)(v.y - (float)h.y);
  h.z = (__bf16)v.z; l.z = (__bf16)(v.z - (float)h.z);
  h.w = (__bf16)v.w; l.w = (__bf16)(v.w - (float)h.w);
  ((bf16x4*)hi)[i] = h;
  ((bf16x4*)lo)[i] = l;
}

// ---------------------------------------------------------------------------
// W^T transpose + split: T[z][c][i] = W[z*256 + i][c] as bf16 hi/lo.
// ---------------------------------------------------------------------------
__global__ __launch_bounds__(256) void wt_split_kernel(const float* __restrict__ W,
                                                       __bf16* __restrict__ Th,
                                                       __bf16* __restrict__ Tl)
{
  const int z = blockIdx.z;
  const float* Wb = W + ((size_t)z << 16);
  __shared__ float t[64][65];
  const int i0 = blockIdx.x * 64, c0 = blockIdx.y * 64;
  const int tr = threadIdx.x >> 6;
  const int tc = threadIdx.x & 63;
#pragma unroll
  for (int rr = 0; rr < 64; rr += 4)
    t[rr + tr][tc] = Wb[(size_t)(i0 + rr + tr) * 256 + c0 + tc];
  __syncthreads();
  __bf16* Thb = Th + ((size_t)z << 16);
  __bf16* Tlb = Tl + ((size_t)z << 16);
#pragma unroll
  for (int cc = 0; cc < 64; cc += 4) {
    const int c = cc + tr, i = tc;
    const float v = t[i][c];
    const __bf16 h = (__bf16)v;
    Thb[(size_t)(c0 + c) * 256 + i0 + i] = h;
    Tlb[(size_t)(c0 + c) * 256 + i0 + i] = (__bf16)(v - (float)h);
  }
}

// ---------------------------------------------------------------------------
// P[h] = WkT[h] @ WqT[h]^T, split-bf16 3-MFMA, output hi/lo.
// ---------------------------------------------------------------------------
__global__ __launch_bounds__(256) void pp_mfma_kernel(
    const __bf16* __restrict__ Th, const __bf16* __restrict__ Tl,
    __bf16* __restrict__ Phi, __bf16* __restrict__ Plo)
{
  const int h = blockIdx.z;
  const __bf16* Ah = Th + ((size_t)(8 + h) << 16);
  const __bf16* Al = Tl + ((size_t)(8 + h) << 16);
  const __bf16* Bh = Th + ((size_t)h << 16);
  const __bf16* Bl = Tl + ((size_t)h << 16);

  __shared__ __bf16 AsH[128 * 32], AsL[128 * 32], BsH[128 * 32], BsL[128 * 32];

  const int tid = threadIdx.x, lane = tid & 63, wid = tid >> 6;
  const int wr = wid >> 1, wc = wid & 1;
  const int bM = blockIdx.y * 128, bN = blockIdx.x * 128;

  const int srow = wid * 16 + (lane >> 2);
  const int scol = (lane & 3) * 8;
  const __bf16* gAh = Ah + (size_t)(bM + srow) * CC + scol;
  const __bf16* gAl = Al + (size_t)(bM + srow) * CC + scol;
  const __bf16* gBh = Bh + (size_t)(bN + srow) * CC + scol;
  const __bf16* gBl = Bl + (size_t)(bN + srow) * CC + scol;
  char* lAh = (char*)AsH + wid * 16 * 64;
  char* lAl = (char*)AsL + wid * 16 * 64;
  char* lBh = (char*)BsH + wid * 16 * 64;
  char* lBl = (char*)BsL + wid * 16 * 64;

  f32x4 acc[4][4];
  const f32x4 z4 = {0.f, 0.f, 0.f, 0.f};
#pragma unroll
  for (int m = 0; m < 4; ++m)
#pragma unroll
    for (int n = 0; n < 4; ++n) acc[m][n] = z4;

  for (int k0 = 0; k0 < CC; k0 += 32) {
    async16(gAh + k0, lAh); async16(gAh + k0 + 64 * CC, lAh + 64 * 64);
    async16(gAl + k0, lAl); async16(gAl + k0 + 64 * CC, lAl + 64 * 64);
    async16(gBh + k0, lBh); async16(gBh + k0 + 64 * CC, lBh + 64 * 64);
    async16(gBl + k0, lBl); async16(gBl + k0 + 64 * CC, lBl + 64 * 64);
    __syncthreads();

    bf16x8 ah[4], al[4], bh_[4], bl_[4];
    const int fb = (lane & 15) * 64 + (lane >> 4) * 16;
#pragma unroll
    for (int m = 0; m < 4; ++m) {
      ah[m] = *(const bf16x8*)((const char*)AsH + (wr * 64 + m * 16) * 64 + fb);
      al[m] = *(const bf16x8*)((const char*)AsL + (wr * 64 + m * 16) * 64 + fb);
    }
#pragma unroll
    for (int n = 0; n < 4; ++n) {
      bh_[n] = *(const bf16x8*)((const char*)BsH + (wc * 64 + n * 16) * 64 + fb);
      bl_[n] = *(const bf16x8*)((const char*)BsL + (wc * 64 + n * 16) * 64 + fb);
    }
#pragma unroll
    for (int m = 0; m < 4; ++m)
#pragma unroll
      for (int n = 0; n < 4; ++n) {
        acc[m][n] = __builtin_amdgcn_mfma_f32_16x16x32_bf16(al[m], bh_[n], acc[m][n], 0, 0, 0);
        acc[m][n] = __builtin_amdgcn_mfma_f32_16x16x32_bf16(ah[m], bl_[n], acc[m][n], 0, 0, 0);
        acc[m][n] = __builtin_amdgcn_mfma_f32_16x16x32_bf16(ah[m], bh_[n], acc[m][n], 0, 0, 0);
      }
    __syncthreads();
  }

  const int fr = lane & 15;
  const int fq = lane >> 4;
#pragma unroll
  for (int m = 0; m < 4; ++m) {
    const int row0 = h * 256 + bM + wr * 64 + m * 16 + fq * 4;
#pragma unroll
    for (int n = 0; n < 4; ++n) {
      const int col = bN + wc * 64 + n * 16 + fr;
#pragma unroll
      for (int r = 0; r < 4; ++r) {
        const float v = acc[m][n][r];
        const __bf16 hh = (__bf16)v;
        Phi[(size_t)(row0 + r) * CC + col] = hh;
        Plo[(size_t)(row0 + r) * CC + col] = (__bf16)(v - (float)hh);
      }
    }
  }
}

// ---------------------------------------------------------------------------
// y = x @ P^T : [8192, 2048], split-bf16 3-MFMA, output hi/lo planes.
// ---------------------------------------------------------------------------
__global__ __launch_bounds__(256) void y_mfma_kernel(
    const __bf16* __restrict__ Ah, const __bf16* __restrict__ Al,
    const __bf16* __restrict__ Bh, const __bf16* __restrict__ Bl,
    __bf16* __restrict__ Chi, __bf16* __restrict__ Clo)
{
  __shared__ __bf16 AsH[128 * 32], AsL[128 * 32], BsH[128 * 32], BsL[128 * 32];

  const int tid = threadIdx.x, lane = tid & 63, wid = tid >> 6;
  const int wr = wid >> 1, wc = wid & 1;
  const int bM = blockIdx.y * 128, bN = blockIdx.x * 128;

  const int srow = wid * 16 + (lane >> 2);
  const int scol = (lane & 3) * 8;
  const __bf16* gAh = Ah + (size_t)(bM + srow) * CC + scol;
  const __bf16* gAl = Al + (size_t)(bM + srow) * CC + scol;
  const __bf16* gBh = Bh + (size_t)(bN + srow) * CC + scol;
  const __bf16* gBl = Bl + (size_t)(bN + srow) * CC + scol;
  char* lAh = (char*)AsH + wid * 16 * 64;
  char* lAl = (char*)AsL + wid * 16 * 64;
  char* lBh = (char*)BsH + wid * 16 * 64;
  char* lBl = (char*)BsL + wid * 16 * 64;

  f32x4 acc[4][4];
  const f32x4 z = {0.f, 0.f, 0.f, 0.f};
#pragma unroll
  for (int m = 0; m < 4; ++m)
#pragma unroll
    for (int n = 0; n < 4; ++n) acc[m][n] = z;

  for (int k0 = 0; k0 < CC; k0 += 32) {
    async16(gAh + k0, lAh); async16(gAh + k0 + 64 * CC, lAh + 64 * 64);
    async16(gAl + k0, lAl); async16(gAl + k0 + 64 * CC, lAl + 64 * 64);
    async16(gBh + k0, lBh); async16(gBh + k0 + 64 * CC, lBh + 64 * 64);
    async16(gBl + k0, lBl); async16(gBl + k0 + 64 * CC, lBl + 64 * 64);
    __syncthreads();

    bf16x8 ah[4], al[4], bh_[4], bl_[4];
    const int fb = (lane & 15) * 64 + (lane >> 4) * 16;
#pragma unroll
    for (int m = 0; m < 4; ++m) {
      ah[m] = *(const bf16x8*)((const char*)AsH + (wr * 64 + m * 16) * 64 + fb);
      al[m] = *(const bf16x8*)((const char*)AsL + (wr * 64 + m * 16) * 64 + fb);
    }
#pragma unroll
    for (int n = 0; n < 4; ++n) {
      bh_[n] = *(const bf16x8*)((const char*)BsH + (wc * 64 + n * 16) * 64 + fb);
      bl_[n] = *(const bf16x8*)((const char*)BsL + (wc * 64 + n * 16) * 64 + fb);
    }
#pragma unroll
    for (int m = 0; m < 4; ++m)
#pragma unroll
      for (int n = 0; n < 4; ++n) {
        acc[m][n] = __builtin_amdgcn_mfma_f32_16x16x32_bf16(al[m], bh_[n], acc[m][n], 0, 0, 0);
        acc[m][n] = __builtin_amdgcn_mfma_f32_16x16x32_bf16(ah[m], bl_[n], acc[m][n], 0, 0, 0);
        acc[m][n] = __builtin_amdgcn_mfma_f32_16x16x32_bf16(ah[m], bh_[n], acc[m][n], 0, 0, 0);
      }
    __syncthreads();
  }

  const int fr = lane & 15;
  const int fq = lane >> 4;
#pragma unroll
  for (int m = 0; m < 4; ++m) {
    const int row0 = bM + wr * 64 + m * 16 + fq * 4;
#pragma unroll
    for (int n = 0; n < 4; ++n) {
      const int col = bN + wc * 64 + n * 16 + fr;
#pragma unroll
      for (int r = 0; r < 4; ++r) {
        const float v = acc[m][n][r];
        const __bf16 h = (__bf16)v;
        Chi[(size_t)(row0 + r) * YC + col] = h;
        Clo[(size_t)(row0 + r) * YC + col] = (__bf16)(v - (float)h);
      }
    }
  }
}

// ---------------------------------------------------------------------------
// logits[b,h] = (1/16) * y_bh @ x_b^T -> f32.  Double-buffered LDS +
// raw s_barrier + counted vmcnt(8): next tile's 8 global_load_lds stay
// in flight across the 48-MFMA phase. bh-resident XCD swizzle.
// ---------------------------------------------------------------------------
__global__ __launch_bounds__(256) void qkt_mfma_kernel(
    const __bf16* __restrict__ Yh, const __bf16* __restrict__ Yl,
    const __bf16* __restrict__ Xh, const __bf16* __restrict__ Xl,
    float* __restrict__ outall)
{
  const int f = blockIdx.x;
  const int xcd = f & 7;
  const int g = f >> 3;
  const int bh = xcd + 8 * (g >> 6);
  const int tile = g & 63;
  const int b = bh >> 3, h = bh & 7;
  const size_t aoff = (size_t)b * NN * YC + (size_t)h * CC;
  const size_t boff = (size_t)b * NN * CC;
  float* C = outall + ((size_t)bh << 20);

  __shared__ __bf16 AsH[2][128 * 32], AsL[2][128 * 32];
  __shared__ __bf16 BsH[2][128 * 32], BsL[2][128 * 32];

  const int tid = threadIdx.x, lane = tid & 63, wid = tid >> 6;
  const int wr = wid >> 1, wc = wid & 1;
  const int bM = (tile >> 3) * 128, bN = (tile & 7) * 128;

  const int srow = wid * 16 + (lane >> 2);
  const int scol = (lane & 3) * 8;
  const __bf16* gAh = Yh + aoff + (size_t)(bM + srow) * YC + scol;
  const __bf16* gAl = Yl + aoff + (size_t)(bM + srow) * YC + scol;
  const __bf16* gBh = Xh + boff + (size_t)(bN + srow) * CC + scol;
  const __bf16* gBl = Xl + boff + (size_t)(bN + srow) * CC + scol;
  const int lofs = wid * 16 * 64;

  f32x4 acc[4][4];
  const f32x4 z = {0.f, 0.f, 0.f, 0.f};
#pragma unroll
  for (int m = 0; m < 4; ++m)
#pragma unroll
    for (int n = 0; n < 4; ++n) acc[m][n] = z;

  const int fb = (lane & 15) * 64 + (lane >> 4) * 16;

#define QKT_STAGE(buf, k0_)                                                    \
  do {                                                                         \
    async16(gAh + (k0_), (char*)AsH[buf] + lofs);                              \
    async16(gAh + (k0_) + (size_t)64 * YC, (char*)AsH[buf] + lofs + 64 * 64);  \
    async16(gAl + (k0_), (char*)AsL[buf] + lofs);                              \
    async16(gAl + (k0_) + (size_t)64 * YC, (char*)AsL[buf] + lofs + 64 * 64);  \
    async16(gBh + (k0_), (char*)BsH[buf] + lofs);                              \
    async16(gBh + (k0_) + (size_t)64 * CC, (char*)BsH[buf] + lofs + 64 * 64);  \
    async16(gBl + (k0_), (char*)BsL[buf] + lofs);                              \
    async16(gBl + (k0_) + (size_t)64 * CC, (char*)BsL[buf] + lofs + 64 * 64);  \
  } while (0)

#define QKT_COMPUTE(buf)                                                       \
  do {                                                                         \
    bf16x8 ah[4], al[4], bh_[4], bl_[4];                                       \
    _Pragma("unroll")                                                          \
    for (int m = 0; m < 4; ++m) {                                              \
      ah[m] = *(const bf16x8*)((const char*)AsH[buf] + (wr * 64 + m * 16) * 64 + fb); \
      al[m] = *(const bf16x8*)((const char*)AsL[buf] + (wr * 64 + m * 16) * 64 + fb); \
    }                                                                          \
    _Pragma("unroll")                                                          \
    for (int n = 0; n < 4; ++n) {                                              \
      bh_[n] = *(const bf16x8*)((const char*)BsH[buf] + (wc * 64 + n * 16) * 64 + fb); \
      bl_[n] = *(const bf16x8*)((const char*)BsL[buf] + (wc * 64 + n * 16) * 64 + fb); \
    }                                                                          \
    _Pragma("unroll")                                                          \
    for (int m = 0; m < 4; ++m)                                                \
      _Pragma("unroll")                                                        \
      for (int n = 0; n < 4; ++n) {                                            \
        acc[m][n] = __builtin_amdgcn_mfma_f32_16x16x32_bf16(al[m], bh_[n], acc[m][n], 0, 0, 0); \
        acc[m][n] = __builtin_amdgcn_mfma_f32_16x16x32_bf16(ah[m], bl_[n], acc[m][n], 0, 0, 0); \
        acc[m][n] = __builtin_amdgcn_mfma_f32_16x16x32_bf16(ah[m], bh_[n], acc[m][n], 0, 0, 0); \
      }                                                                        \
  } while (0)

  // prologue
  QKT_STAGE(0, 0);

  int cur = 0;
#pragma unroll 1
  for (int k0 = 0; k0 < CC - 32; k0 += 32) {
    QKT_STAGE(cur ^ 1, k0 + 32);
    asm volatile("s_waitcnt vmcnt(8)" ::: "memory");
    __builtin_amdgcn_s_barrier();
    __builtin_amdgcn_sched_barrier(0);
    QKT_COMPUTE(cur);
    __builtin_amdgcn_s_barrier();
    __builtin_amdgcn_sched_barrier(0);
    cur ^= 1;
  }
  asm volatile("s_waitcnt vmcnt(0)" ::: "memory");
  __builtin_amdgcn_s_barrier();
  __builtin_amdgcn_sched_barrier(0);
  QKT_COMPUTE(cur);

#undef QKT_STAGE
#undef QKT_COMPUTE

  const int fr = lane & 15;
  const int fq = lane >> 4;
#pragma unroll
  for (int m = 0; m < 4; ++m) {
    const int row0 = bM + wr * 64 + m * 16 + fq * 4;
#pragma unroll
    for (int n = 0; n < 4; ++n) {
      const int col = bN + wc * 64 + n * 16 + fr;
#pragma unroll
      for (int r = 0; r < 4; ++r)
        C[(size_t)(row0 + r) * NN + col] = acc[m][n][r] * 0.0625f;
    }
  }
}

// ---------------------------------------------------------------------------
// Fused softmax + head-sum. f32 logits in, bf16 attn -> ws (contig).
// ---------------------------------------------------------------------------
__global__ __launch_bounds__(256) void softmax_se_kernel(const float* __restrict__ logits,
                                                         __bf16* __restrict__ attnb,
                                                         float* __restrict__ se)
{
  const int bn = blockIdx.x;
  const int b = bn >> 10;
  const int n = bn & 1023;
  const int t = threadIdx.x;
  const int lane = t & 63, wv = t >> 6;
  __shared__ float wred[4];
  float4 acc = make_float4(0.f, 0.f, 0.f, 0.f);

#pragma unroll 1
  for (int h = 0; h < HH; ++h) {
    const size_t rowbase = (((size_t)(b * HH + h) << 10) + n) << 10;
    const float* ar = logits + rowbase;
    __bf16* arb = attnb + rowbase;
    float4 x = *(const float4*)(ar + (t << 2));
    float mx = waveMax(fmaxf(fmaxf(x.x, x.y), fmaxf(x.z, x.w)));
    if (lane == 0) wred[wv] = mx;
    __syncthreads();
    const float M = fmaxf(fmaxf(wred[0], wred[1]), fmaxf(wred[2], wred[3]));
    __syncthreads();

    float e0 = expf(x.x - M), e1 = expf(x.y - M), e2 = expf(x.z - M), e3 = expf(x.w - M);
    float s = waveSum(e0 + e1 + e2 + e3);
    if (lane == 0) wred[wv] = s;
    __syncthreads();
    const float inv = 1.0f / (wred[0] + wred[1] + wred[2] + wred[3]);

    const float o0 = e0 * inv, o1 = e1 * inv, o2 = e2 * inv, o3 = e3 * inv;
    bf16x4 ob; ob.x = (__bf16)o0; ob.y = (__bf16)o1; ob.z = (__bf16)o2; ob.w = (__bf16)o3;
    *(bf16x4*)(arb + (t << 2)) = ob;
    acc.x += o0; acc.y += o1; acc.z += o2; acc.w += o3;
    __syncthreads();
  }
  *(float4*)(se + (size_t)bn * NN + (t << 2)) = acc;
}

// ---------------------------------------------------------------------------
// Top-5 per row of sum_edge; colmask[b, idx] = 1 for each winner.
// ---------------------------------------------------------------------------
__global__ __launch_bounds__(256) void topk_kernel(const float* __restrict__ se,
                                                   float* __restrict__ colmask)
{
  const int bn = blockIdx.x;
  const int b = bn >> 10;
  const int t = threadIdx.x;
  __shared__ float vals[NN];
  __shared__ unsigned long long red[256];
  const float* rowp = se + (size_t)bn * NN;
  for (int i = t; i < NN; i += 256) vals[i] = rowp[i];
  __syncthreads();

  for (int it = 0; it < 5; ++it) {
    unsigned long long best = 0ull;
    for (int i = t; i < NN; i += 256) {
      const float v = vals[i];
      if (v >= 0.f) {
        unsigned long long key =
            ((unsigned long long)__float_as_uint(v) << 32) | (unsigned)(NN - 1 - i);
        if (key > best) best = key;
      }
    }
    red[t] = best; __syncthreads();
    for (int s = 128; s > 0; s >>= 1) {
      if (t < s) red[t] = red[t] > red[t+s] ? red[t] : red[t+s];
      __syncthreads();
    }
    if (t == 0) {
      const int idx = NN - 1 - (int)(red[0] & 0xFFFFFFFFull);
      colmask[b * NN + idx] = 1.0f;
      vals[idx] = -1.0f;
    }
    __syncthreads();
  }
}

// ---------------------------------------------------------------------------
// Fused rs+cs stage 1. Grid (16, B*H).
// ---------------------------------------------------------------------------
__global__ __launch_bounds__(256) void cs_rs_kernel(const __bf16* __restrict__ attnb,
                                                    const float* __restrict__ colmask,
                                                    float* __restrict__ inv_rs,
                                                    float* __restrict__ part)
{
  const int bh = blockIdx.y;
  const int b = bh >> 3;
  const int chunk = blockIdx.x;
  const int t = threadIdx.x, lane = t & 63, wv = t >> 6;
  const __bf16* ab = attnb + ((size_t)bh << 20);
  const float* cm = colmask + b * NN;
  const int c0 = lane * 16;

  float cmv[16];
#pragma unroll
  for (int q = 0; q < 4; ++q) {
    const float4 c4 = *(const float4*)(cm + c0 + q * 4);
    cmv[q*4+0] = c4.x; cmv[q*4+1] = c4.y; cmv[q*4+2] = c4.z; cmv[q*4+3] = c4.w;
  }

  float a[16];
#pragma unroll
  for (int j = 0; j < 16; ++j) a[j] = 0.f;

  const int nbase = chunk * 64 + wv * 16;
#pragma unroll 1
  for (int r = 0; r < 16; ++r) {
    const int n = nbase + r;
    const __bf16* rowp = ab + ((size_t)n << 10) + c0;
    const bf16x8 v0 = *(const bf16x8*)(rowp);
    const bf16x8 v1 = *(const bf16x8*)(rowp + 8);
    float e[16];
    float rsum = 0.f;
#pragma unroll
    for (int j = 0; j < 8; ++j) {
      const float val = ((cmv[j] != 0.f) || (c0 + j == n)) ? (float)v0[j] : 0.f;
      e[j] = val; rsum += val;
    }
#pragma unroll
    for (int j = 0; j < 8; ++j) {
      const float val = ((cmv[8+j] != 0.f) || (c0 + 8 + j == n)) ? (float)v1[j] : 0.f;
      e[8+j] = val; rsum += val;
    }
    rsum = waveSum(rsum);
    const float ir = 1.0f / (rsum + 1e-16f);
    if (lane == 0) inv_rs[bh * NN + n] = ir;
#pragma unroll
    for (int j = 0; j < 16; ++j) a[j] += e[j] * ir;
  }

  __shared__ float l[4][NN];
#pragma unroll
  for (int j = 0; j < 16; ++j) l[wv][c0 + j] = a[j];
  __syncthreads();
  const int m0 = t << 2;
  float4 o;
  o.x = l[0][m0+0] + l[1][m0+0] + l[2][m0+0] + l[3][m0+0];
  o.y = l[0][m0+1] + l[1][m0+1] + l[2][m0+1] + l[3][m0+1];
  o.z = l[0][m0+2] + l[1][m0+2] + l[2][m0+2] + l[3][m0+2];
  o.w = l[0][m0+3] + l[1][m0+3] + l[2][m0+3] + l[3][m0+3];
  *(float4*)(part + (((size_t)chunk * (BB*HH) + bh) << 10) + m0) = o;
}

// ---------------------------------------------------------------------------
__global__ __launch_bounds__(256) void cs_fin_kernel(const float* __restrict__ part,
                                                     float* __restrict__ isc)
{
  const int bh = blockIdx.x;
  const int m0 = threadIdx.x << 2;
  float a0 = 0.f, a1 = 0.f, a2 = 0.f, a3 = 0.f;
#pragma unroll
  for (int c = 0; c < 16; ++c) {
    const float4 p = *(const float4*)(part + (((size_t)c * (BB*HH) + bh) << 10) + m0);
    a0 += p.x; a1 += p.y; a2 += p.z; a3 += p.w;
  }
  float4 o;
  o.x = 1.0f / sqrtf(a0 + 1e-16f);
  o.y = 1.0f / sqrtf(a1 + 1e-16f);
  o.z = 1.0f / sqrtf(a2 + 1e-16f);
  o.w = 1.0f / sqrtf(a3 + 1e-16f);
  *(float4*)(isc + ((size_t)bh << 10) + m0) = o;
}

// ---------------------------------------------------------------------------
// Gb = bf16( e * inv_rs[n] * isc[m] ), 8 elems/thread (16B loads/stores).
// ---------------------------------------------------------------------------
__global__ __launch_bounds__(256) void g_kernel(const __bf16* __restrict__ attnb,
                                                const float* __restrict__ colmask,
                                                const float* __restrict__ inv_rs,
                                                const float* __restrict__ isc,
                                                __bf16* __restrict__ Gb)
{
  const size_t idx = ((size_t)blockIdx.x * 256 + threadIdx.x) << 3;
  const size_t row = idx >> 10;
  const int m = (int)(idx & 1023);
  const int n = (int)(row & 1023);
  const int bh = (int)(row >> 10);
  const int b = bh >> 3;
  const bf16x8 vb = *(const bf16x8*)(attnb + idx);
  const float4 c0 = *(const float4*)(colmask + b * NN + m);
  const float4 c1 = *(const float4*)(colmask + b * NN + m + 4);
  const float4 s0 = *(const float4*)(isc + ((size_t)bh << 10) + m);
  const float4 s1 = *(const float4*)(isc + ((size_t)bh << 10) + m + 4);
  const float ir = inv_rs[row];
  const float cm[8] = {c0.x, c0.y, c0.z, c0.w, c1.x, c1.y, c1.z, c1.w};
  const float sc[8] = {s0.x, s0.y, s0.z, s0.w, s1.x, s1.y, s1.z, s1.w};
  bf16x8 o;
#pragma unroll
  for (int j = 0; j < 8; ++j) {
    const float e = ((cm[j] != 0.f) || (m + j == n)) ? (float)vb[j] : 0.f;
    o[j] = (__bf16)(e * ir * sc[j]);
  }
  *(bf16x8*)(Gb + idx) = o;
}

// ---------------------------------------------------------------------------
// out[b,h] = Gb @ Gb^T (symmetric, dbuf + counted vmcnt(4), XCD swizzle).
// ---------------------------------------------------------------------------
__global__ __launch_bounds__(256) void ggt_mfma_kernel(const __bf16* __restrict__ Gball,
                                                       float* __restrict__ outall)
{
  const int f = blockIdx.x;
  const int xcd = f & 7;
  const int g = f >> 3;
  const int bh = xcd + 8 * (g / 36);
  int tt = g % 36;

  const __bf16* A = Gball + ((size_t)bh << 20);
  float* C = outall + ((size_t)bh << 20);

  int ti = 0;
#pragma unroll
  for (int r = 0; r < 8; ++r) {
    const int len = 8 - r;
    if (tt < len) { ti = r; break; }
    tt -= len;
  }
  const int tj = ti + tt;

  __shared__ __bf16 As[2][128 * 32];
  __shared__ __bf16 Bs[2][128 * 32];

  const int tid  = threadIdx.x;
  const int lane = tid & 63;
  const int wid  = tid >> 6;
  const int wr   = wid >> 1;
  const int wc   = wid & 1;
  const int bM   = ti * 128;
  const int bN   = tj * 128;

  const int srow = wid * 16 + (lane >> 2);
  const int scol = (lane & 3) * 8;
  const __bf16* gA = A + (size_t)(bM + srow) * NN + scol;
  const __bf16* gB = A + (size_t)(bN + srow) * NN + scol;
  const int lofs = wid * 16 * 64;

  f32x4 acc[4][4];
  const f32x4 z = {0.f, 0.f, 0.f, 0.f};
#pragma unroll
  for (int m = 0; m < 4; ++m)
#pragma unroll
    for (int n = 0; n < 4; ++n) acc[m][n] = z;

  const int fb = (lane & 15) * 64 + (lane >> 4) * 16;

  async16(gA,           (char*)As[0] + lofs);
  async16(gA + 64 * NN, (char*)As[0] + lofs + 64 * 64);
  async16(gB,           (char*)Bs[0] + lofs);
  async16(gB + 64 * NN, (char*)Bs[0] + lofs + 64 * 64);

  int cur = 0;
#pragma unroll 1
  for (int k0 = 0; k0 < NN - 32; k0 += 32) {
    const int nxt = cur ^ 1;
    async16(gA + k0 + 32,           (char*)As[nxt] + lofs);
    async16(gA + k0 + 32 + 64 * NN, (char*)As[nxt] + lofs + 64 * 64);
    async16(gB + k0 + 32,           (char*)Bs[nxt] + lofs);
    async16(gB + k0 + 32 + 64 * NN, (char*)Bs[nxt] + lofs + 64 * 64);
    asm volatile("s_waitcnt vmcnt(4)" ::: "memory");
    __builtin_amdgcn_s_barrier();
    __builtin_amdgcn_sched_barrier(0);

    bf16x8 a[4], b[4];
#pragma unroll
    for (int m = 0; m < 4; ++m)
      a[m] = *(const bf16x8*)((const char*)As[cur] + (wr * 64 + m * 16) * 64 + fb);
#pragma unroll
    for (int n = 0; n < 4; ++n)
      b[n] = *(const bf16x8*)((const char*)Bs[cur] + (wc * 64 + n * 16) * 64 + fb);
#pragma unroll
    for (int m = 0; m < 4; ++m)
#pragma unroll
      for (int n = 0; n < 4; ++n)
        acc[m][n] = __builtin_amdgcn_mfma_f32_16x16x32_bf16(a[m], b[n], acc[m][n], 0, 0, 0);
    __builtin_amdgcn_s_barrier();
    __builtin_amdgcn_sched_barrier(0);
    cur ^= 1;
  }

  asm volatile("s_waitcnt vmcnt(0)" ::: "memory");
  __builtin_amdgcn_s_barrier();
  __builtin_amdgcn_sched_barrier(0);
  {
    bf16x8 a[4], b[4];
#pragma unroll
    for (int m = 0; m < 4; ++m)
      a[m] = *(const bf16x8*)((const char*)As[cur] + (wr * 64 + m * 16) * 64 + fb);
#pragma unroll
    for (int n = 0; n < 4; ++n)
      b[n] = *(const bf16x8*)((const char*)Bs[cur] + (wc * 64 + n * 16) * 64 + fb);
#pragma unroll
    for (int m = 0; m < 4; ++m)
#pragma unroll
      for (int n = 0; n < 4; ++n)
        acc[m][n] = __builtin_amdgcn_mfma_f32_16x16x32_bf16(a[m], b[n], acc[m][n], 0, 0, 0);
  }

  const int fr = lane & 15;
  const int fq = lane >> 4;
#pragma unroll
  for (int m = 0; m < 4; ++m) {
    const int row0 = bM + wr * 64 + m * 16 + fq * 4;
#pragma unroll
    for (int n = 0; n < 4; ++n) {
      const int col = bN + wc * 64 + n * 16 + fr;
#pragma unroll
      for (int r = 0; r < 4; ++r)
        C[(size_t)(row0 + r) * NN + col] = acc[m][n][r];
    }
  }
  if (ti != tj) {
#pragma unroll
    for (int m = 0; m < 4; ++m) {
      const int colT = bM + wr * 64 + m * 16 + fq * 4;
#pragma unroll
      for (int n = 0; n < 4; ++n) {
        const int rowT = bN + wc * 64 + n * 16 + fr;
        *(f32x4*)(C + (size_t)rowT * NN + colT) = acc[m][n];
      }
    }
  }
}

// ---------------------------------------------------------------------------
extern "C" void kernel_launch(void* const* d_in, const int* in_sizes, int n_in,
                              void* d_out, int out_size, void* d_ws, size_t ws_size,
                              hipStream_t stream)
{
  const float* x = (const float*)d_in[0];   // [B,N,C]
  const float* W = (const float*)d_in[1];   // [2*H*C, C]
  float* logits = (float*)d_out;
  char* ws = (char*)d_ws;

  __bf16* y_hi  = (__bf16*)(ws + ((size_t)0   << 20));   // 32 MiB [8192,2048]
  __bf16* y_lo  = (__bf16*)(ws + ((size_t)32  << 20));   // 32 MiB
  __bf16* attnb = (__bf16*)(ws + ((size_t)0   << 20));   // 128 MiB (reuses y after qkt)
  __bf16* x_hi  = (__bf16*)(ws + ((size_t)128 << 20));   // 4 MiB
  __bf16* x_lo  = (__bf16*)(ws + ((size_t)132 << 20));   // 4 MiB
  __bf16* T_hi  = (__bf16*)(ws + ((size_t)136 << 20));   // 2 MiB  [16,256,256]
  __bf16* T_lo  = (__bf16*)(ws + ((size_t)138 << 20));   // 2 MiB
  __bf16* P_hi  = (__bf16*)(ws + ((size_t)140 << 20));   // 1 MiB  [2048,256]
  __bf16* P_lo  = (__bf16*)(ws + ((size_t)142 << 20));   // 1 MiB
  float*  se    = (float*)(ws + ((size_t)144 << 20));    // 32 MiB
  float*  cmask = (float*)(ws + ((size_t)176 << 20));
  float*  irs   = (float*)(ws + ((size_t)177 << 20));
  float*  isc   = (float*)(ws + ((size_t)178 << 20));
  float*  csp   = (float*)(ws + ((size_t)180 << 20));    // 4 MiB
  __bf16* Gb    = (__bf16*)(ws + ((size_t)192 << 20));   // 128 MiB

  // 0a. split x -> hi/lo
  hipLaunchKernelGGL(split_kernel, dim3(BB*NN*CC/4/256), dim3(256), 0, stream,
                     x, x_hi, x_lo);
  // 0b. W^T transpose + split
  hipLaunchKernelGGL(wt_split_kernel, dim3(4, 4, 16), dim3(256), 0, stream,
                     W, T_hi, T_lo);
  // 0c. P[h] = WkT @ WqT^T
  hipLaunchKernelGGL(pp_mfma_kernel, dim3(2, 2, 8), dim3(256), 0, stream,
                     T_hi, T_lo, P_hi, P_lo);

  // 1. y = x @ P^T
  hipLaunchKernelGGL(y_mfma_kernel, dim3(YC/128, (BB*NN)/128, 1), dim3(256), 0, stream,
                     x_hi, x_lo, P_hi, P_lo, y_hi, y_lo);

  // 2. logits = (1/16) y @ x^T (dbuf + counted vmcnt, bh swizzle)
  hipLaunchKernelGGL(qkt_mfma_kernel, dim3(64 * 64), dim3(256), 0, stream,
                     y_hi, y_lo, x_hi, x_lo, logits);

  // 3+4. softmax + head-sum
  hipLaunchKernelGGL(softmax_se_kernel, dim3(BB*NN), dim3(256), 0, stream,
                     logits, attnb, se);

  // 5. top-5 union -> column mask
  hipMemsetAsync(cmask, 0, (size_t)BB * NN * 4, stream);
  hipLaunchKernelGGL(topk_kernel, dim3(BB*NN), dim3(256), 0, stream, se, cmask);

  // 6+7. fused row sums + column partials, then finalize isc
  hipLaunchKernelGGL(cs_rs_kernel, dim3(16, BB*HH), dim3(256), 0, stream,
                     attnb, cmask, irs, csp);
  hipLaunchKernelGGL(cs_fin_kernel, dim3(BB*HH), dim3(256), 0, stream, csp, isc);

  // 8. Gb = bf16( e * inv_rs * isc )
  hipLaunchKernelGGL(g_kernel, dim3((BB*HH*NN*(long long)NN) / 8 / 256), dim3(256), 0, stream,
                     attnb, cmask, irs, isc, Gb);

  // 9. out = Gb @ Gb^T (symmetric MFMA, dbuf+counted-vmcnt, bh swizzle)
  hipLaunchKernelGGL(ggt_mfma_kernel, dim3(36 * 64), dim3(256), 0, stream,
                     Gb, logits);

  (void)in_sizes; (void)n_in; (void)out_size; (void)ws_size;
}